// Round 1
// baseline (922.847 us; speedup 1.0000x reference)
//
#include <hip/hip_runtime.h>
#include <math.h>

#define EPSF 1e-8f
#define WIN_LEN 256
#define HOP 128
#define NFFT 512
#define NBINS 257          // rfft bins of 512
#define NUMBAND 15
#define NFRAMES 2499       // (320000-256)/128+1
#define NSTFT 2498         // NFRAMES-1
#define N_INTEL 30
#define NSEG 2469          // NSTFT - N_INTEL + 1
#define NB 32              // batch
#define T_LEN 320000
#define CLIP_VAL 5.623413251903491f   // 10^(15/20)

// ---- workspace layout (bytes) ----
// counts  : 0          (32 int)
// band_lo : 512        (16 int)  [15] = min over bands
// band_hi : 768        (16 int)  [15] = max over bands (exclusive)
// acc     : 1024       (32 float)
// srcfrm  : 2048       (32*2499 int = 319872 B)
// xtob    : 324096     (32*15*2498 float = 4796160 B)
// ytob    : 5120512    (same)
// end ~ 9.92 MB
#define WS_COUNTS   0
#define WS_BANDLO   512
#define WS_BANDHI   768
#define WS_ACC      1024
#define WS_SRCFRM   2048
#define WS_XTOB     324096
#define WS_YTOB     5120512

__global__ __launch_bounds__(256)
void k1_mask_scan(const float* __restrict__ tgt, const float* __restrict__ win,
                  const float* __restrict__ obm,
                  int* __restrict__ counts, int* __restrict__ srcfrm,
                  int* __restrict__ band_lo, int* __restrict__ band_hi,
                  float* __restrict__ acc)
{
    const int b = blockIdx.x;
    const int tid = threadIdx.x;
    __shared__ float nrm[NFRAMES];
    __shared__ float red[256];
    __shared__ int   cnt[256];
    __shared__ int   excl[257];

    const float* x = tgt + (size_t)b * T_LEN;
    for (int f = tid; f < NFRAMES; f += 256) {
        const float* xp = x + f * HOP;
        float s = 0.f;
        #pragma unroll 8
        for (int t = 0; t < WIN_LEN; ++t) {
            float v = xp[t] * win[t];
            s = fmaf(v, v, s);
        }
        nrm[f] = sqrtf(s);
    }
    __syncthreads();

    // max-reduce over frame norms
    float mx = 0.f;
    for (int f = tid; f < NFRAMES; f += 256) mx = fmaxf(mx, nrm[f]);
    red[tid] = mx;
    __syncthreads();
    for (int s = 128; s > 0; s >>= 1) {
        if (tid < s) red[tid] = fmaxf(red[tid], red[tid + s]);
        __syncthreads();
    }
    const float thr = (red[0] + EPSF) * 0.01f;   // 10^(-40/20)

    // chunked compaction scan (stable order)
    const int c0 = tid * 10;
    const int c1 = (c0 + 10 < NFRAMES) ? c0 + 10 : NFRAMES;
    int lc = 0;
    for (int f = c0; f < c1; ++f) if (nrm[f] + EPSF > thr) ++lc;
    cnt[tid] = lc;
    __syncthreads();
    if (tid == 0) {
        int run = 0;
        for (int i = 0; i < 256; ++i) { excl[i] = run; run += cnt[i]; }
        excl[256] = run;
        counts[b] = run;
        acc[b] = 0.f;   // self-init accumulator every launch
    }
    __syncthreads();
    int pos = excl[tid];
    int* sf = srcfrm + b * NFRAMES;
    for (int f = c0; f < c1; ++f) if (nrm[f] + EPSF > thr) sf[pos++] = f;

    // band bin ranges from obm (block 0 only)
    if (b == 0 && tid < NUMBAND) {
        int lo = -1, hi = 0;
        for (int k = 0; k < NBINS; ++k) {
            if (obm[tid * NBINS + k] != 0.f) { if (lo < 0) lo = k; hi = k + 1; }
        }
        band_lo[tid] = (lo < 0) ? 0 : lo;
        band_hi[tid] = hi;
    }
    __syncthreads();
    if (b == 0 && tid == 0) {
        int lo = NBINS, hi = 0;
        for (int i = 0; i < NUMBAND; ++i) {
            if (band_lo[i] < lo) lo = band_lo[i];
            if (band_hi[i] > hi) hi = band_hi[i];
        }
        band_lo[NUMBAND] = lo;
        band_hi[NUMBAND] = hi;
    }
}

__global__ __launch_bounds__(256)
void k2_stft_tob(const float* __restrict__ est, const float* __restrict__ tgt,
                 const float* __restrict__ win,
                 const int* __restrict__ counts, const int* __restrict__ srcfrm,
                 const int* __restrict__ band_lo, const int* __restrict__ band_hi,
                 float* __restrict__ xtob, float* __restrict__ ytob)
{
    const int j = blockIdx.x;     // STFT frame index 0..NSTFT-1
    const int b = blockIdx.y;
    const int cntb = counts[b];
    if (j >= cntb - 1) return;    // frame masked (m[j]=0); never consumed downstream

    const int tid = threadIdx.x;
    __shared__ float xs[WIN_LEN], ys[WIN_LEN];
    __shared__ float px[NBINS],  py[NBINS];

    const int* sf = srcfrm + b * NFRAMES;
    const float* xg = tgt + (size_t)b * T_LEN;
    const float* yg = est + (size_t)b * T_LEN;

    // Build OLA-reconstructed STFT frame sample t=tid directly:
    // x_sil[j*HOP+t] = fr[j][t] + (t<HOP ? fr[j-1][HOP+t] : fr[j+1][t-HOP]), fr[-1]=0
    // fr[k][u] = sig[srcfrm[k]*HOP + u] * win[u]; then second window win[t].
    {
        const int t = tid;
        const float w = win[t];
        const int k0 = sf[j];
        float xv = xg[k0 * HOP + t] * w;
        float yv = yg[k0 * HOP + t] * w;
        if (t < HOP) {
            if (j >= 1) {
                const int km = sf[j - 1];
                const float w2 = win[HOP + t];
                xv = fmaf(xg[km * HOP + HOP + t], w2, xv);
                yv = fmaf(yg[km * HOP + HOP + t], w2, yv);
            }
        } else {
            const int kp = sf[j + 1];        // j+1 <= counts-1: valid
            const float w2 = win[t - HOP];
            xv = fmaf(xg[kp * HOP + t - HOP], w2, xv);
            yv = fmaf(yg[kp * HOP + t - HOP], w2, yv);
        }
        xs[t] = xv * w;
        ys[t] = yv * w;
    }
    __syncthreads();

    // Direct DFT (n=512, real input of 256 samples) for the bins bands need.
    const int blo = band_lo[NUMBAND];
    const int bhi = band_hi[NUMBAND];
    const float step = -6.283185307179586f / 512.f;
    for (int bin = blo + tid; bin < bhi; bin += 256) {
        const float ang = step * (float)bin;
        const float ck = cosf(ang), sk = sinf(ang);
        float c = 1.f, s = 0.f;
        float axr = 0.f, axi = 0.f, ayr = 0.f, ayi = 0.f;
        #pragma unroll 8
        for (int t = 0; t < WIN_LEN; ++t) {
            const float xv = xs[t], yv = ys[t];
            axr = fmaf(xv, c, axr); axi = fmaf(xv, s, axi);
            ayr = fmaf(yv, c, ayr); ayi = fmaf(yv, s, ayi);
            const float cn = fmaf(c, ck, -(s * sk));
            s = fmaf(s, ck, c * sk);
            c = cn;
        }
        px[bin] = fmaf(axr, axr, axi * axi);
        py[bin] = fmaf(ayr, ayr, ayi * ayi);
    }
    __syncthreads();

    // Third-octave band sums -> sqrt(E + EPS)
    if (tid < NUMBAND) {
        float ssum = 0.f;
        const int lo = band_lo[tid], hi = band_hi[tid];
        for (int k = lo; k < hi; ++k) ssum += px[k];
        xtob[((size_t)b * NUMBAND + tid) * NSTFT + j] = sqrtf(ssum + EPSF);
    } else if (tid >= 32 && tid < 32 + NUMBAND) {
        const int band = tid - 32;
        float ssum = 0.f;
        const int lo = band_lo[band], hi = band_hi[band];
        for (int k = lo; k < hi; ++k) ssum += py[k];
        ytob[((size_t)b * NUMBAND + band) * NSTFT + j] = sqrtf(ssum + EPSF);
    }
}

__global__ __launch_bounds__(256)
void k3_corr(const float* __restrict__ xtob, const float* __restrict__ ytob,
             const int* __restrict__ counts, float* __restrict__ acc)
{
    const int bb = blockIdx.y;            // b*NUMBAND + band
    const int b = bb / NUMBAND;
    const int band = bb % NUMBAND;
    const int seg = blockIdx.x * 256 + threadIdx.x;

    int nvalid = counts[b] - N_INTEL;
    if (nvalid < 0) nvalid = 0;
    if (nvalid > NSEG) nvalid = NSEG;

    float d = 0.f;
    if (seg < nvalid) {
        const float* xr = xtob + ((size_t)b * NUMBAND + band) * NSTFT + seg;
        const float* yr = ytob + ((size_t)b * NUMBAND + band) * NSTFT + seg;
        float xv[N_INTEL], yv[N_INTEL];
        float sx2 = 0.f, sy2 = 0.f;
        #pragma unroll
        for (int i = 0; i < N_INTEL; ++i) {
            xv[i] = xr[i]; yv[i] = yr[i];
            sx2 = fmaf(xv[i], xv[i], sx2);
            sy2 = fmaf(yv[i], yv[i], sy2);
        }
        const float nc = sqrtf(sx2) / (sqrtf(sy2) + EPSF);
        float sy = 0.f, sx = 0.f;
        #pragma unroll
        for (int i = 0; i < N_INTEL; ++i) {
            const float yp = fminf(yv[i] * nc, xv[i] * (1.f + CLIP_VAL));
            yv[i] = yp;
            sy += yp; sx += xv[i];
        }
        const float my = sy * (1.f / N_INTEL);
        const float mxm = sx * (1.f / N_INTEL);
        float num = 0.f, dy = 0.f, dx2 = 0.f;
        #pragma unroll
        for (int i = 0; i < N_INTEL; ++i) {
            const float a = yv[i] - my;
            const float c = xv[i] - mxm;
            num = fmaf(a, c, num);
            dy  = fmaf(a, a, dy);
            dx2 = fmaf(c, c, dx2);
        }
        d = num / ((sqrtf(dy) + EPSF) * (sqrtf(dx2) + EPSF));
    }

    // block reduce then one atomic per block
    #pragma unroll
    for (int o = 32; o > 0; o >>= 1) d += __shfl_down(d, o, 64);
    __shared__ float wsum[4];
    const int lane = threadIdx.x & 63, wid = threadIdx.x >> 6;
    if (lane == 0) wsum[wid] = d;
    __syncthreads();
    if (threadIdx.x == 0) {
        atomicAdd(&acc[b], wsum[0] + wsum[1] + wsum[2] + wsum[3]);
    }
}

__global__ void k4_final(const float* __restrict__ acc, const int* __restrict__ counts,
                         float* __restrict__ out)
{
    const int b = threadIdx.x;
    if (b < NB) {
        int nvalid = counts[b] - N_INTEL;
        if (nvalid < 0) nvalid = 0;
        if (nvalid > NSEG) nvalid = NSEG;
        out[b] = -(acc[b] * (1.f / NUMBAND)) / ((float)nvalid + EPSF);
    }
}

extern "C" void kernel_launch(void* const* d_in, const int* in_sizes, int n_in,
                              void* d_out, int out_size, void* d_ws, size_t ws_size,
                              hipStream_t stream) {
    (void)in_sizes; (void)n_in; (void)out_size; (void)ws_size;
    const float* est = (const float*)d_in[0];   // est_targets (32,320000)
    const float* tgt = (const float*)d_in[1];   // targets     (32,320000)
    const float* win = (const float*)d_in[2];   // (256,)
    const float* obm = (const float*)d_in[3];   // (15,257)
    float* out = (float*)d_out;                 // (32,)

    char* ws = (char*)d_ws;
    int*   counts  = (int*)(ws + WS_COUNTS);
    int*   band_lo = (int*)(ws + WS_BANDLO);
    int*   band_hi = (int*)(ws + WS_BANDHI);
    float* acc     = (float*)(ws + WS_ACC);
    int*   srcfrm  = (int*)(ws + WS_SRCFRM);
    float* xtob    = (float*)(ws + WS_XTOB);
    float* ytob    = (float*)(ws + WS_YTOB);

    k1_mask_scan<<<dim3(NB), dim3(256), 0, stream>>>(tgt, win, obm, counts, srcfrm,
                                                     band_lo, band_hi, acc);
    k2_stft_tob<<<dim3(NSTFT, NB), dim3(256), 0, stream>>>(est, tgt, win, counts, srcfrm,
                                                           band_lo, band_hi, xtob, ytob);
    k3_corr<<<dim3((NSEG + 255) / 256, NB * NUMBAND), dim3(256), 0, stream>>>(xtob, ytob,
                                                                              counts, acc);
    k4_final<<<1, NB, 0, stream>>>(acc, counts, out);
}

// Round 2
// 394.766 us; speedup vs baseline: 2.3377x; 2.3377x over previous
//
#include <hip/hip_runtime.h>
#include <math.h>

#define EPSF 1e-8f
#define WIN_LEN 256
#define HOP 128
#define NFFT 512
#define NBINS 257          // rfft bins of 512
#define NUMBAND 15
#define NFRAMES 2499       // (320000-256)/128+1
#define NSTFT 2498         // NFRAMES-1
#define N_INTEL 30
#define NSEG 2469          // NSTFT - N_INTEL + 1
#define NB 32              // batch
#define T_LEN 320000
#define CLIP_VAL 5.623413251903491f   // 10^(15/20)

// ---- workspace layout (bytes) ----
#define WS_COUNTS   0
#define WS_BANDLO   512
#define WS_BANDHI   768
#define WS_ACC      1024
#define WS_SRCFRM   2048
#define WS_XTOB     324096
#define WS_YTOB     5120512

__global__ __launch_bounds__(256)
void k1_mask_scan(const float* __restrict__ tgt, const float* __restrict__ win,
                  const float* __restrict__ obm,
                  int* __restrict__ counts, int* __restrict__ srcfrm,
                  int* __restrict__ band_lo, int* __restrict__ band_hi,
                  float* __restrict__ acc)
{
    const int b = blockIdx.x;
    const int tid = threadIdx.x;
    __shared__ float nrm[NFRAMES];
    __shared__ float red[256];
    __shared__ int   cnt[256];
    __shared__ int   excl[257];

    const float* x = tgt + (size_t)b * T_LEN;
    for (int f = tid; f < NFRAMES; f += 256) {
        const float* xp = x + f * HOP;
        float s = 0.f;
        #pragma unroll 8
        for (int t = 0; t < WIN_LEN; ++t) {
            float v = xp[t] * win[t];
            s = fmaf(v, v, s);
        }
        nrm[f] = sqrtf(s);
    }
    __syncthreads();

    // max-reduce over frame norms
    float mx = 0.f;
    for (int f = tid; f < NFRAMES; f += 256) mx = fmaxf(mx, nrm[f]);
    red[tid] = mx;
    __syncthreads();
    for (int s = 128; s > 0; s >>= 1) {
        if (tid < s) red[tid] = fmaxf(red[tid], red[tid + s]);
        __syncthreads();
    }
    const float thr = (red[0] + EPSF) * 0.01f;   // 10^(-40/20)

    // chunked compaction scan (stable order)
    const int c0 = tid * 10;
    const int c1 = (c0 + 10 < NFRAMES) ? c0 + 10 : NFRAMES;
    int lc = 0;
    for (int f = c0; f < c1; ++f) if (nrm[f] + EPSF > thr) ++lc;
    cnt[tid] = lc;
    __syncthreads();
    if (tid == 0) {
        int run = 0;
        for (int i = 0; i < 256; ++i) { excl[i] = run; run += cnt[i]; }
        excl[256] = run;
        counts[b] = run;
        acc[b] = 0.f;   // self-init accumulator every launch
    }
    __syncthreads();
    int pos = excl[tid];
    int* sf = srcfrm + b * NFRAMES;
    for (int f = c0; f < c1; ++f) if (nrm[f] + EPSF > thr) sf[pos++] = f;

    // band bin ranges from obm (block 0 only)
    if (b == 0 && tid < NUMBAND) {
        int lo = -1, hi = 0;
        for (int k = 0; k < NBINS; ++k) {
            if (obm[tid * NBINS + k] != 0.f) { if (lo < 0) lo = k; hi = k + 1; }
        }
        band_lo[tid] = (lo < 0) ? 0 : lo;
        band_hi[tid] = hi;
    }
    __syncthreads();
    if (b == 0 && tid == 0) {
        int lo = NBINS, hi = 0;
        for (int i = 0; i < NUMBAND; ++i) {
            if (band_lo[i] < lo) lo = band_lo[i];
            if (band_hi[i] > hi) hi = band_hi[i];
        }
        band_lo[NUMBAND] = lo;
        band_hi[NUMBAND] = hi;
    }
}

// Two-stage factorized DFT (512 = 32 x 16), real input of 256 samples.
// Stage 1: S[t0][m] = sum_{t1<16} x[16*t1+t0] * W32^{m*t1}   (t0<16, m<32)
// Stage 2: X[k]     = sum_{t0<16} W512^{k*t0} * S[t0][k&31]
__global__ __launch_bounds__(256)
void k2_stft_tob(const float* __restrict__ est, const float* __restrict__ tgt,
                 const float* __restrict__ win,
                 const int* __restrict__ counts, const int* __restrict__ srcfrm,
                 const int* __restrict__ band_lo, const int* __restrict__ band_hi,
                 float* __restrict__ xtob, float* __restrict__ ytob)
{
    const int j = blockIdx.x;     // STFT frame index 0..NSTFT-1
    const int b = blockIdx.y;
    const int cntb = counts[b];
    if (j >= cntb - 1) return;    // frame masked (m[j]=0); never consumed downstream

    const int tid = threadIdx.x;
    __shared__ float2 fr[WIN_LEN];        // (x, y) packed
    __shared__ float2 SX[512], SY[512];   // stage-1 output, (re, im), idx = t0*32+m
    __shared__ float  px[NBINS], py[NBINS];

    const int* sf = srcfrm + b * NFRAMES;
    const float* xg = tgt + (size_t)b * T_LEN;
    const float* yg = est + (size_t)b * T_LEN;

    // Build OLA-reconstructed STFT frame sample t=tid:
    // x_sil[j*HOP+t] = fr[j][t] + (t<HOP ? fr[j-1][HOP+t] : fr[j+1][t-HOP]), fr[-1]=0
    // fr[k][u] = sig[srcfrm[k]*HOP + u] * win[u]; then second window win[t].
    {
        const int t = tid;
        const float w = win[t];
        const int k0 = sf[j];
        float xv = xg[k0 * HOP + t] * w;
        float yv = yg[k0 * HOP + t] * w;
        if (t < HOP) {
            if (j >= 1) {
                const int km = sf[j - 1];
                const float w2 = win[HOP + t];
                xv = fmaf(xg[km * HOP + HOP + t], w2, xv);
                yv = fmaf(yg[km * HOP + HOP + t], w2, yv);
            }
        } else {
            const int kp = sf[j + 1];        // j+1 <= counts-1: valid
            const float w2 = win[t - HOP];
            xv = fmaf(xg[kp * HOP + t - HOP], w2, xv);
            yv = fmaf(yg[kp * HOP + t - HOP], w2, yv);
        }
        fr[t] = make_float2(xv * w, yv * w);
    }
    __syncthreads();

    // ---- Stage 1: each thread does one m (shared twiddle), two t0, both signals
    {
        const int m   = tid & 31;
        const int t0a = tid >> 5;      // 0..7
        const int t0b = t0a + 8;
        const float ang = -0.19634954084936207f * (float)m;  // -pi/16 * m
        const float ck = cosf(ang), sk = sinf(ang);
        float c = 1.f, s = 0.f;
        float xar = 0.f, xai = 0.f, xbr = 0.f, xbi = 0.f;
        float yar = 0.f, yai = 0.f, ybr = 0.f, ybi = 0.f;
        #pragma unroll
        for (int t1 = 0; t1 < 16; ++t1) {
            const float2 va = fr[t1 * 16 + t0a];
            const float2 vb = fr[t1 * 16 + t0b];
            xar = fmaf(va.x, c, xar); xai = fmaf(va.x, s, xai);
            yar = fmaf(va.y, c, yar); yai = fmaf(va.y, s, yai);
            xbr = fmaf(vb.x, c, xbr); xbi = fmaf(vb.x, s, xbi);
            ybr = fmaf(vb.y, c, ybr); ybi = fmaf(vb.y, s, ybi);
            const float cn = fmaf(c, ck, -(s * sk));
            s = fmaf(s, ck, c * sk);
            c = cn;
        }
        SX[t0a * 32 + m] = make_float2(xar, xai);
        SY[t0a * 32 + m] = make_float2(yar, yai);
        SX[t0b * 32 + m] = make_float2(xbr, xbi);
        SY[t0b * 32 + m] = make_float2(ybr, ybi);
    }
    __syncthreads();

    // ---- Stage 2: one bin per thread, both signals
    const int blo = band_lo[NUMBAND];
    const int bhi = band_hi[NUMBAND];
    {
        const int k = blo + tid;
        if (k < bhi) {
            const int m = k & 31;
            const float ang = -0.012271846303085130f * (float)k;  // -pi/256 * k
            const float ck = cosf(ang), sk = sinf(ang);
            float c = 1.f, s = 0.f;
            float xr = 0.f, xi = 0.f, yr = 0.f, yi = 0.f;
            #pragma unroll
            for (int t0 = 0; t0 < 16; ++t0) {
                const float2 sx = SX[t0 * 32 + m];
                const float2 sy = SY[t0 * 32 + m];
                xr = fmaf(sx.x, c, fmaf(-sx.y, s, xr));
                xi = fmaf(sx.x, s, fmaf( sx.y, c, xi));
                yr = fmaf(sy.x, c, fmaf(-sy.y, s, yr));
                yi = fmaf(sy.x, s, fmaf( sy.y, c, yi));
                const float cn = fmaf(c, ck, -(s * sk));
                s = fmaf(s, ck, c * sk);
                c = cn;
            }
            px[k] = fmaf(xr, xr, xi * xi);
            py[k] = fmaf(yr, yr, yi * yi);
        }
    }
    __syncthreads();

    // Third-octave band sums -> sqrt(E + EPS)
    if (tid < NUMBAND) {
        float ssum = 0.f;
        const int lo = band_lo[tid], hi = band_hi[tid];
        for (int k = lo; k < hi; ++k) ssum += px[k];
        xtob[((size_t)b * NUMBAND + tid) * NSTFT + j] = sqrtf(ssum + EPSF);
    } else if (tid >= 32 && tid < 32 + NUMBAND) {
        const int band = tid - 32;
        float ssum = 0.f;
        const int lo = band_lo[band], hi = band_hi[band];
        for (int k = lo; k < hi; ++k) ssum += py[k];
        ytob[((size_t)b * NUMBAND + band) * NSTFT + j] = sqrtf(ssum + EPSF);
    }
}

__global__ __launch_bounds__(256)
void k3_corr(const float* __restrict__ xtob, const float* __restrict__ ytob,
             const int* __restrict__ counts, float* __restrict__ acc)
{
    const int bb = blockIdx.y;            // b*NUMBAND + band
    const int b = bb / NUMBAND;
    const int band = bb % NUMBAND;
    const int seg = blockIdx.x * 256 + threadIdx.x;

    int nvalid = counts[b] - N_INTEL;
    if (nvalid < 0) nvalid = 0;
    if (nvalid > NSEG) nvalid = NSEG;

    float d = 0.f;
    if (seg < nvalid) {
        const float* xr = xtob + ((size_t)b * NUMBAND + band) * NSTFT + seg;
        const float* yr = ytob + ((size_t)b * NUMBAND + band) * NSTFT + seg;
        float xv[N_INTEL], yv[N_INTEL];
        float sx2 = 0.f, sy2 = 0.f;
        #pragma unroll
        for (int i = 0; i < N_INTEL; ++i) {
            xv[i] = xr[i]; yv[i] = yr[i];
            sx2 = fmaf(xv[i], xv[i], sx2);
            sy2 = fmaf(yv[i], yv[i], sy2);
        }
        const float nc = sqrtf(sx2) / (sqrtf(sy2) + EPSF);
        float sy = 0.f, sx = 0.f;
        #pragma unroll
        for (int i = 0; i < N_INTEL; ++i) {
            const float yp = fminf(yv[i] * nc, xv[i] * (1.f + CLIP_VAL));
            yv[i] = yp;
            sy += yp; sx += xv[i];
        }
        const float my = sy * (1.f / N_INTEL);
        const float mxm = sx * (1.f / N_INTEL);
        float num = 0.f, dy = 0.f, dx2 = 0.f;
        #pragma unroll
        for (int i = 0; i < N_INTEL; ++i) {
            const float a = yv[i] - my;
            const float c = xv[i] - mxm;
            num = fmaf(a, c, num);
            dy  = fmaf(a, a, dy);
            dx2 = fmaf(c, c, dx2);
        }
        d = num / ((sqrtf(dy) + EPSF) * (sqrtf(dx2) + EPSF));
    }

    // block reduce then one atomic per block
    #pragma unroll
    for (int o = 32; o > 0; o >>= 1) d += __shfl_down(d, o, 64);
    __shared__ float wsum[4];
    const int lane = threadIdx.x & 63, wid = threadIdx.x >> 6;
    if (lane == 0) wsum[wid] = d;
    __syncthreads();
    if (threadIdx.x == 0) {
        atomicAdd(&acc[b], wsum[0] + wsum[1] + wsum[2] + wsum[3]);
    }
}

__global__ void k4_final(const float* __restrict__ acc, const int* __restrict__ counts,
                         float* __restrict__ out)
{
    const int b = threadIdx.x;
    if (b < NB) {
        int nvalid = counts[b] - N_INTEL;
        if (nvalid < 0) nvalid = 0;
        if (nvalid > NSEG) nvalid = NSEG;
        out[b] = -(acc[b] * (1.f / NUMBAND)) / ((float)nvalid + EPSF);
    }
}

extern "C" void kernel_launch(void* const* d_in, const int* in_sizes, int n_in,
                              void* d_out, int out_size, void* d_ws, size_t ws_size,
                              hipStream_t stream) {
    (void)in_sizes; (void)n_in; (void)out_size; (void)ws_size;
    const float* est = (const float*)d_in[0];   // est_targets (32,320000)
    const float* tgt = (const float*)d_in[1];   // targets     (32,320000)
    const float* win = (const float*)d_in[2];   // (256,)
    const float* obm = (const float*)d_in[3];   // (15,257)
    float* out = (float*)d_out;                 // (32,)

    char* ws = (char*)d_ws;
    int*   counts  = (int*)(ws + WS_COUNTS);
    int*   band_lo = (int*)(ws + WS_BANDLO);
    int*   band_hi = (int*)(ws + WS_BANDHI);
    float* acc     = (float*)(ws + WS_ACC);
    int*   srcfrm  = (int*)(ws + WS_SRCFRM);
    float* xtob    = (float*)(ws + WS_XTOB);
    float* ytob    = (float*)(ws + WS_YTOB);

    k1_mask_scan<<<dim3(NB), dim3(256), 0, stream>>>(tgt, win, obm, counts, srcfrm,
                                                     band_lo, band_hi, acc);
    k2_stft_tob<<<dim3(NSTFT, NB), dim3(256), 0, stream>>>(est, tgt, win, counts, srcfrm,
                                                           band_lo, band_hi, xtob, ytob);
    k3_corr<<<dim3((NSEG + 255) / 256, NB * NUMBAND), dim3(256), 0, stream>>>(xtob, ytob,
                                                                              counts, acc);
    k4_final<<<1, NB, 0, stream>>>(acc, counts, out);
}

// Round 3
// 298.356 us; speedup vs baseline: 3.0931x; 1.3231x over previous
//
#include <hip/hip_runtime.h>
#include <math.h>

#define EPSF 1e-8f
#define WIN_LEN 256
#define HOP 128
#define NBINS 257          // rfft bins of 512
#define NUMBAND 15
#define NFRAMES 2499       // (320000-256)/128+1
#define NSTFT 2498         // NFRAMES-1
#define N_INTEL 30
#define NSEG 2469          // NSTFT - N_INTEL + 1
#define NB 32              // batch
#define T_LEN 320000
#define CLIP_VAL 5.623413251903491f   // 10^(15/20)
#define NRM_STRIDE 2560

typedef float v2f __attribute__((ext_vector_type(2)));
typedef float v4f __attribute__((ext_vector_type(4)));

// ---- packed fp32 helpers (VOP3P) ----
// d += a * bcast(b.lo)
__device__ __forceinline__ void pk_fma_blo(v2f& d, v2f a, v2f b) {
    asm("v_pk_fma_f32 %0, %1, %2, %0 op_sel:[0,0,0] op_sel_hi:[1,0,1]"
        : "+v"(d) : "v"(a), "v"(b));
}
// d += a * bcast(b.hi)
__device__ __forceinline__ void pk_fma_bhi(v2f& d, v2f a, v2f b) {
    asm("v_pk_fma_f32 %0, %1, %2, %0 op_sel:[0,1,0] op_sel_hi:[1,1,1]"
        : "+v"(d) : "v"(a), "v"(b));
}
// d += (-a.hi*b.hi, a.lo*b.hi)   (complex rotate-accumulate, imag term)
__device__ __forceinline__ void pk_fma_rot(v2f& d, v2f a, v2f b) {
    asm("v_pk_fma_f32 %0, %1, %2, %0 op_sel:[1,1,0] op_sel_hi:[0,1,1] neg_lo:[1,0,0]"
        : "+v"(d) : "v"(a), "v"(b));
}
// cs = (cs.lo*ck - cs.hi*sk, cs.hi*ck + cs.lo*sk), cksk = (ck, sk)
__device__ __forceinline__ void pk_rot(v2f& cs, v2f cksk) {
    v2f t;
    asm("v_pk_mul_f32 %0, %1, %2 op_sel:[0,0] op_sel_hi:[1,0]"
        : "=v"(t) : "v"(cs), "v"(cksk));                 // (c*ck, s*ck)
    asm("v_pk_fma_f32 %0, %0, %1, %2 op_sel:[1,1,0] op_sel_hi:[0,1,1] neg_lo:[1,0,0]"
        : "+v"(cs) : "v"(cksk), "v"(t));                 // (-s*sk + c*ck, c*sk + s*ck)
}

// ---- workspace layout (bytes) ----
#define WS_COUNTS   0
#define WS_BANDLO   512
#define WS_BANDHI   768
#define WS_ACC      1024
#define WS_SRCFRM   2048
#define WS_XTOB     324096     // nrm scratch aliases this region (consumed before k2)
#define WS_YTOB     5120512

__global__ __launch_bounds__(256)
void k1a_norms(const float* __restrict__ tgt, const float* __restrict__ win,
               float* __restrict__ nrm)
{
    const int b = blockIdx.x;
    const int blk = blockIdx.y;
    const int tid = threadIdx.x;
    const int frame = blk * 128 + (tid >> 1);
    const int half = tid & 1;
    if (frame >= NFRAMES) return;   // partner lane exits too (same frame)

    const float* xp = tgt + (size_t)b * T_LEN + (size_t)(frame + half) * HOP;
    const float* wp = win + half * HOP;
    float s = 0.f;
    #pragma unroll 8
    for (int t = 0; t < HOP; t += 4) {
        const float4 xv = *(const float4*)(xp + t);
        const float4 wv = *(const float4*)(wp + t);
        float v0 = xv.x * wv.x, v1 = xv.y * wv.y, v2 = xv.z * wv.z, v3 = xv.w * wv.w;
        s = fmaf(v0, v0, s); s = fmaf(v1, v1, s);
        s = fmaf(v2, v2, s); s = fmaf(v3, v3, s);
    }
    s += __shfl_xor(s, 1, 64);
    if (half == 0) nrm[(size_t)b * NRM_STRIDE + frame] = sqrtf(s);
}

__global__ __launch_bounds__(256)
void k1b_scan(const float* __restrict__ nrm, const float* __restrict__ obm,
              int* __restrict__ counts, int* __restrict__ srcfrm,
              int* __restrict__ band_lo, int* __restrict__ band_hi,
              float* __restrict__ acc)
{
    const int b = blockIdx.x;
    const int tid = threadIdx.x;
    __shared__ float nr[NFRAMES];
    __shared__ float red[256];
    __shared__ int   cnt[256];
    __shared__ int   excl[257];

    const float* np_ = nrm + (size_t)b * NRM_STRIDE;
    for (int f = tid; f < NFRAMES; f += 256) nr[f] = np_[f];
    __syncthreads();

    float mx = 0.f;
    for (int f = tid; f < NFRAMES; f += 256) mx = fmaxf(mx, nr[f]);
    red[tid] = mx;
    __syncthreads();
    for (int s = 128; s > 0; s >>= 1) {
        if (tid < s) red[tid] = fmaxf(red[tid], red[tid + s]);
        __syncthreads();
    }
    const float thr = (red[0] + EPSF) * 0.01f;   // 10^(-40/20)

    const int c0 = tid * 10;
    const int c1 = (c0 + 10 < NFRAMES) ? c0 + 10 : NFRAMES;
    int lc = 0;
    for (int f = c0; f < c1; ++f) if (nr[f] + EPSF > thr) ++lc;
    cnt[tid] = lc;
    __syncthreads();
    if (tid == 0) {
        int run = 0;
        for (int i = 0; i < 256; ++i) { excl[i] = run; run += cnt[i]; }
        counts[b] = run;
        acc[b] = 0.f;   // self-init accumulator every launch
    }
    __syncthreads();
    int pos = excl[tid];
    int* sf = srcfrm + b * NFRAMES;
    for (int f = c0; f < c1; ++f) if (nr[f] + EPSF > thr) sf[pos++] = f;

    if (b == 0 && tid < NUMBAND) {
        int lo = -1, hi = 0;
        for (int k = 0; k < NBINS; ++k) {
            if (obm[tid * NBINS + k] != 0.f) { if (lo < 0) lo = k; hi = k + 1; }
        }
        band_lo[tid] = (lo < 0) ? 0 : lo;
        band_hi[tid] = hi;
    }
    __syncthreads();
    if (b == 0 && tid == 0) {
        int lo = NBINS, hi = 0;
        for (int i = 0; i < NUMBAND; ++i) {
            if (band_lo[i] < lo) lo = band_lo[i];
            if (band_hi[i] > hi) hi = band_hi[i];
        }
        band_lo[NUMBAND] = lo;
        band_hi[NUMBAND] = hi;
    }
}

// Two-stage factorized DFT (512 = 32 x 16), real input of 256 samples, both
// signals packed. Stage 1: S[t0][m] = sum_{t1<16} x[16*t1+t0] * W32^{m*t1}
// Stage 2: X[k] = sum_{t0<16} W512^{k*t0} * S[t0][k&31]
__global__ __launch_bounds__(256)
void k2_stft_tob(const float* __restrict__ est, const float* __restrict__ tgt,
                 const float* __restrict__ win,
                 const int* __restrict__ counts, const int* __restrict__ srcfrm,
                 const int* __restrict__ band_lo, const int* __restrict__ band_hi,
                 float* __restrict__ xtob, float* __restrict__ ytob)
{
    const int j = blockIdx.x;
    const int b = blockIdx.y;
    const int cntb = counts[b];
    if (j >= cntb - 1) return;    // masked frame; never consumed downstream

    const int tid = threadIdx.x;
    __shared__ float frf[WIN_LEN * 2];      // interleaved (x, y) per sample
    __shared__ v4f   sxy[512];              // {x.re, x.im, y.re, y.im}, idx t0*32+m
    __shared__ float px[NBINS], py[NBINS];

    const int* sf = srcfrm + b * NFRAMES;
    const float* xg = tgt + (size_t)b * T_LEN;
    const float* yg = est + (size_t)b * T_LEN;

    // OLA-reconstructed STFT frame, sample t = tid (see round-1 derivation)
    {
        const int t = tid;
        const float w = win[t];
        const int k0 = sf[j];
        float xv = xg[k0 * HOP + t] * w;
        float yv = yg[k0 * HOP + t] * w;
        if (t < HOP) {
            if (j >= 1) {
                const int km = sf[j - 1];
                const float w2 = win[HOP + t];
                xv = fmaf(xg[km * HOP + HOP + t], w2, xv);
                yv = fmaf(yg[km * HOP + HOP + t], w2, yv);
            }
        } else {
            const int kp = sf[j + 1];
            const float w2 = win[t - HOP];
            xv = fmaf(xg[kp * HOP + t - HOP], w2, xv);
            yv = fmaf(yg[kp * HOP + t - HOP], w2, yv);
        }
        v2f pr = { xv * w, yv * w };
        *(v2f*)&frf[2 * t] = pr;
    }
    __syncthreads();

    // ---- Stage 1: thread = (m, t0 pair {2g, 2g+1}); both signals packed
    {
        const int m = tid & 31;
        const int g = tid >> 5;            // 0..7
        const float ang = -0.19634954084936207f * (float)m;  // -pi/16 * m
        const v2f cksk = { __cosf(ang), __sinf(ang) };
        v2f cs = { 1.f, 0.f };
        v2f aR = { 0.f, 0.f }, aI = { 0.f, 0.f };   // t0 = 2g   : (x,y) re / im
        v2f bR = { 0.f, 0.f }, bI = { 0.f, 0.f };   // t0 = 2g+1
        #pragma unroll
        for (int t1 = 0; t1 < 16; ++t1) {
            const v4f vv = *(const v4f*)&frf[4 * (t1 * 8 + g)];  // x0,y0,x1,y1
            const v2f va = vv.xy;
            const v2f vb = vv.zw;
            pk_fma_blo(aR, va, cs);
            pk_fma_bhi(aI, va, cs);
            pk_fma_blo(bR, vb, cs);
            pk_fma_bhi(bI, vb, cs);
            pk_rot(cs, cksk);
        }
        v4f sa = { aR.x, aI.x, aR.y, aI.y };
        v4f sb = { bR.x, bI.x, bR.y, bI.y };
        sxy[(2 * g) * 32 + m] = sa;
        sxy[(2 * g + 1) * 32 + m] = sb;
    }
    __syncthreads();

    // ---- Stage 2: one bin per thread, both signals
    const int blo = band_lo[NUMBAND];
    const int bhi = band_hi[NUMBAND];
    {
        const int k = blo + tid;
        if (k < bhi) {
            const int m = k & 31;
            const float ang = -0.012271846303085130f * (float)k;  // -pi/256 * k
            const v2f cksk = { __cosf(ang), __sinf(ang) };
            v2f cs = { 1.f, 0.f };
            v2f accX = { 0.f, 0.f }, accY = { 0.f, 0.f };   // (re, im)
            #pragma unroll
            for (int t0 = 0; t0 < 16; ++t0) {
                const v4f sv = sxy[t0 * 32 + m];
                const v2f sx = sv.xy;
                const v2f sy = sv.zw;
                pk_fma_blo(accX, cs, sx);   // += (c*re, s*re)
                pk_fma_rot(accX, cs, sx);   // += (-s*im, c*im)
                pk_fma_blo(accY, cs, sy);
                pk_fma_rot(accY, cs, sy);
                pk_rot(cs, cksk);
            }
            px[k] = fmaf(accX.x, accX.x, accX.y * accX.y);
            py[k] = fmaf(accY.x, accY.x, accY.y * accY.y);
        }
    }
    __syncthreads();

    // Third-octave band sums -> sqrt(E + EPS)
    if (tid < NUMBAND) {
        float ssum = 0.f;
        const int lo = band_lo[tid], hi = band_hi[tid];
        for (int k = lo; k < hi; ++k) ssum += px[k];
        xtob[((size_t)b * NUMBAND + tid) * NSTFT + j] = sqrtf(ssum + EPSF);
    } else if (tid >= 32 && tid < 32 + NUMBAND) {
        const int band = tid - 32;
        float ssum = 0.f;
        const int lo = band_lo[band], hi = band_hi[band];
        for (int k = lo; k < hi; ++k) ssum += py[k];
        ytob[((size_t)b * NUMBAND + band) * NSTFT + j] = sqrtf(ssum + EPSF);
    }
}

__global__ __launch_bounds__(256)
void k3_corr(const float* __restrict__ xtob, const float* __restrict__ ytob,
             const int* __restrict__ counts, float* __restrict__ acc)
{
    const int bb = blockIdx.y;
    const int b = bb / NUMBAND;
    const int band = bb % NUMBAND;
    const int seg = blockIdx.x * 256 + threadIdx.x;

    int nvalid = counts[b] - N_INTEL;
    if (nvalid < 0) nvalid = 0;
    if (nvalid > NSEG) nvalid = NSEG;

    float d = 0.f;
    if (seg < nvalid) {
        const float* xr = xtob + ((size_t)b * NUMBAND + band) * NSTFT + seg;
        const float* yr = ytob + ((size_t)b * NUMBAND + band) * NSTFT + seg;
        float xv[N_INTEL], yv[N_INTEL];
        float sx2 = 0.f, sy2 = 0.f;
        #pragma unroll
        for (int i = 0; i < N_INTEL; ++i) {
            xv[i] = xr[i]; yv[i] = yr[i];
            sx2 = fmaf(xv[i], xv[i], sx2);
            sy2 = fmaf(yv[i], yv[i], sy2);
        }
        const float nc = sqrtf(sx2) / (sqrtf(sy2) + EPSF);
        float sy = 0.f, sx = 0.f;
        #pragma unroll
        for (int i = 0; i < N_INTEL; ++i) {
            const float yp = fminf(yv[i] * nc, xv[i] * (1.f + CLIP_VAL));
            yv[i] = yp;
            sy += yp; sx += xv[i];
        }
        const float my = sy * (1.f / N_INTEL);
        const float mxm = sx * (1.f / N_INTEL);
        float num = 0.f, dy = 0.f, dx2 = 0.f;
        #pragma unroll
        for (int i = 0; i < N_INTEL; ++i) {
            const float a = yv[i] - my;
            const float c = xv[i] - mxm;
            num = fmaf(a, c, num);
            dy  = fmaf(a, a, dy);
            dx2 = fmaf(c, c, dx2);
        }
        d = num / ((sqrtf(dy) + EPSF) * (sqrtf(dx2) + EPSF));
    }

    #pragma unroll
    for (int o = 32; o > 0; o >>= 1) d += __shfl_down(d, o, 64);
    __shared__ float wsum[4];
    const int lane = threadIdx.x & 63, wid = threadIdx.x >> 6;
    if (lane == 0) wsum[wid] = d;
    __syncthreads();
    if (threadIdx.x == 0) {
        atomicAdd(&acc[b], wsum[0] + wsum[1] + wsum[2] + wsum[3]);
    }
}

__global__ void k4_final(const float* __restrict__ acc, const int* __restrict__ counts,
                         float* __restrict__ out)
{
    const int b = threadIdx.x;
    if (b < NB) {
        int nvalid = counts[b] - N_INTEL;
        if (nvalid < 0) nvalid = 0;
        if (nvalid > NSEG) nvalid = NSEG;
        out[b] = -(acc[b] * (1.f / NUMBAND)) / ((float)nvalid + EPSF);
    }
}

extern "C" void kernel_launch(void* const* d_in, const int* in_sizes, int n_in,
                              void* d_out, int out_size, void* d_ws, size_t ws_size,
                              hipStream_t stream) {
    (void)in_sizes; (void)n_in; (void)out_size; (void)ws_size;
    const float* est = (const float*)d_in[0];
    const float* tgt = (const float*)d_in[1];
    const float* win = (const float*)d_in[2];
    const float* obm = (const float*)d_in[3];
    float* out = (float*)d_out;

    char* ws = (char*)d_ws;
    int*   counts  = (int*)(ws + WS_COUNTS);
    int*   band_lo = (int*)(ws + WS_BANDLO);
    int*   band_hi = (int*)(ws + WS_BANDHI);
    float* acc     = (float*)(ws + WS_ACC);
    int*   srcfrm  = (int*)(ws + WS_SRCFRM);
    float* xtob    = (float*)(ws + WS_XTOB);
    float* ytob    = (float*)(ws + WS_YTOB);
    float* nrm     = xtob;   // scratch alias: consumed by k1b before k2 writes xtob

    k1a_norms<<<dim3(NB, 20), dim3(256), 0, stream>>>(tgt, win, nrm);
    k1b_scan<<<dim3(NB), dim3(256), 0, stream>>>(nrm, obm, counts, srcfrm,
                                                 band_lo, band_hi, acc);
    k2_stft_tob<<<dim3(NSTFT, NB), dim3(256), 0, stream>>>(est, tgt, win, counts, srcfrm,
                                                           band_lo, band_hi, xtob, ytob);
    k3_corr<<<dim3((NSEG + 255) / 256, NB * NUMBAND), dim3(256), 0, stream>>>(xtob, ytob,
                                                                              counts, acc);
    k4_final<<<1, NB, 0, stream>>>(acc, counts, out);
}

// Round 4
// 271.103 us; speedup vs baseline: 3.4040x; 1.1005x over previous
//
#include <hip/hip_runtime.h>
#include <math.h>

#define EPSF 1e-8f
#define WIN_LEN 256
#define HOP 128
#define NBINS 257          // rfft bins of 512
#define NUMBAND 15
#define NFRAMES 2499       // (320000-256)/128+1
#define NSTFT 2498         // NFRAMES-1
#define N_INTEL 30
#define NSEG 2469          // NSTFT - N_INTEL + 1
#define NB 32              // batch
#define T_LEN 320000
#define CLIP_VAL 5.623413251903491f   // 10^(15/20)
#define NRM_STRIDE 2560

typedef float v2f __attribute__((ext_vector_type(2)));
typedef float v4f __attribute__((ext_vector_type(4)));

// ---- packed fp32 helpers (VOP3P) ----
// d += a * bcast(b.lo)
__device__ __forceinline__ void pk_fma_blo(v2f& d, v2f a, v2f b) {
    asm("v_pk_fma_f32 %0, %1, %2, %0 op_sel:[0,0,0] op_sel_hi:[1,0,1]"
        : "+v"(d) : "v"(a), "v"(b));
}
// d += a * bcast(b.hi)
__device__ __forceinline__ void pk_fma_bhi(v2f& d, v2f a, v2f b) {
    asm("v_pk_fma_f32 %0, %1, %2, %0 op_sel:[0,1,0] op_sel_hi:[1,1,1]"
        : "+v"(d) : "v"(a), "v"(b));
}
// d += (-a.hi*b.hi, a.lo*b.hi)   (complex rotate-accumulate, imag term)
__device__ __forceinline__ void pk_fma_rot(v2f& d, v2f a, v2f b) {
    asm("v_pk_fma_f32 %0, %1, %2, %0 op_sel:[1,1,0] op_sel_hi:[0,1,1] neg_lo:[1,0,0]"
        : "+v"(d) : "v"(a), "v"(b));
}
// cs = cs * (ck + i sk), cksk = (ck, sk)
__device__ __forceinline__ void pk_rot(v2f& cs, v2f cksk) {
    v2f t;
    asm("v_pk_mul_f32 %0, %1, %2 op_sel:[0,0] op_sel_hi:[1,0]"
        : "=v"(t) : "v"(cs), "v"(cksk));                 // (c*ck, s*ck)
    asm("v_pk_fma_f32 %0, %0, %1, %2 op_sel:[1,1,0] op_sel_hi:[0,1,1] neg_lo:[1,0,0]"
        : "+v"(cs) : "v"(cksk), "v"(t));                 // (c*ck - s*sk, s*ck + c*sk)
}

// ---- workspace layout (bytes) ----
#define WS_COUNTS   0
#define WS_BANDLO   512
#define WS_BANDHI   768
#define WS_ACC      1024
#define WS_SRCFRM   2048
#define WS_XTOB     324096     // nrm scratch aliases this region (consumed before k2)
#define WS_YTOB     5120512

__global__ __launch_bounds__(256)
void k1a_norms(const float* __restrict__ tgt, const float* __restrict__ win,
               float* __restrict__ nrm)
{
    const int b = blockIdx.x;
    const int blk = blockIdx.y;
    const int tid = threadIdx.x;
    const int frame = blk * 128 + (tid >> 1);
    const int half = tid & 1;
    if (frame >= NFRAMES) return;   // partner lane exits too (same frame)

    const float* xp = tgt + (size_t)b * T_LEN + (size_t)(frame + half) * HOP;
    const float* wp = win + half * HOP;
    float s = 0.f;
    #pragma unroll 8
    for (int t = 0; t < HOP; t += 4) {
        const float4 xv = *(const float4*)(xp + t);
        const float4 wv = *(const float4*)(wp + t);
        float v0 = xv.x * wv.x, v1 = xv.y * wv.y, v2 = xv.z * wv.z, v3 = xv.w * wv.w;
        s = fmaf(v0, v0, s); s = fmaf(v1, v1, s);
        s = fmaf(v2, v2, s); s = fmaf(v3, v3, s);
    }
    s += __shfl_xor(s, 1, 64);
    if (half == 0) nrm[(size_t)b * NRM_STRIDE + frame] = sqrtf(s);
}

__global__ __launch_bounds__(256)
void k1b_scan(const float* __restrict__ nrm, const float* __restrict__ obm,
              int* __restrict__ counts, int* __restrict__ srcfrm,
              int* __restrict__ band_lo, int* __restrict__ band_hi,
              float* __restrict__ acc)
{
    const int b = blockIdx.x;
    const int tid = threadIdx.x;
    __shared__ float nr[NFRAMES];
    __shared__ float red[256];
    __shared__ int   cnt[256];
    __shared__ int   excl[257];

    const float* np_ = nrm + (size_t)b * NRM_STRIDE;
    for (int f = tid; f < NFRAMES; f += 256) nr[f] = np_[f];
    __syncthreads();

    float mx = 0.f;
    for (int f = tid; f < NFRAMES; f += 256) mx = fmaxf(mx, nr[f]);
    red[tid] = mx;
    __syncthreads();
    for (int s = 128; s > 0; s >>= 1) {
        if (tid < s) red[tid] = fmaxf(red[tid], red[tid + s]);
        __syncthreads();
    }
    const float thr = (red[0] + EPSF) * 0.01f;   // 10^(-40/20)

    const int c0 = tid * 10;
    const int c1 = (c0 + 10 < NFRAMES) ? c0 + 10 : NFRAMES;
    int lc = 0;
    for (int f = c0; f < c1; ++f) if (nr[f] + EPSF > thr) ++lc;
    cnt[tid] = lc;
    __syncthreads();
    if (tid == 0) {
        int run = 0;
        for (int i = 0; i < 256; ++i) { excl[i] = run; run += cnt[i]; }
        counts[b] = run;
        acc[b] = 0.f;   // self-init accumulator every launch
    }
    __syncthreads();
    int pos = excl[tid];
    int* sf = srcfrm + b * NFRAMES;
    for (int f = c0; f < c1; ++f) if (nr[f] + EPSF > thr) sf[pos++] = f;

    if (b == 0 && tid < NUMBAND) {
        int lo = -1, hi = 0;
        for (int k = 0; k < NBINS; ++k) {
            if (obm[tid * NBINS + k] != 0.f) { if (lo < 0) lo = k; hi = k + 1; }
        }
        band_lo[tid] = (lo < 0) ? 0 : lo;
        band_hi[tid] = hi;
    }
    __syncthreads();
    if (b == 0 && tid == 0) {
        int lo = NBINS, hi = 0;
        for (int i = 0; i < NUMBAND; ++i) {
            if (band_lo[i] < lo) lo = band_lo[i];
            if (band_hi[i] > hi) hi = band_hi[i];
        }
        band_lo[NUMBAND] = lo;
        band_hi[NUMBAND] = hi;
    }
}

// Two-stage factorized DFT (512 = 32 x 16), 128 threads/block.
// Stage 1: S[t0][m] = sum_{t1<16} x[16*t1+t0] * W32^{m*t1}; thread = (m<16, g<8)
//   computes m and m+16 via parity split: W32^{(m+16)t1} = W32^{m t1} * (-1)^t1.
// Stage 2: X[k] = sum_{t0<16} W512^{k*t0} * S[t0][k&31]; thread = (m2<32, p<4)
//   computes bins k1 = base+m2+32p and k1+128 (same m2, step2 = step1 * (-i)).
__global__ __launch_bounds__(128)
void k2_stft_tob(const float* __restrict__ est, const float* __restrict__ tgt,
                 const float* __restrict__ win,
                 const int* __restrict__ counts, const int* __restrict__ srcfrm,
                 const int* __restrict__ band_lo, const int* __restrict__ band_hi,
                 float* __restrict__ xtob, float* __restrict__ ytob)
{
    // bijective XCD-chunked remap: consecutive j share an XCD (kills xtob
    // write false-sharing across XCD L2s; improves signal-read L2 reuse)
    const int lin = blockIdx.x;
    const int xcd = lin & 7, cidx = lin >> 3;
    const int q = NSTFT >> 3, r = NSTFT & 7;
    const int j = (xcd < r ? xcd * (q + 1) : r * (q + 1) + (xcd - r) * q) + cidx;

    const int b = blockIdx.y;
    const int cntb = counts[b];
    if (j >= cntb - 1) return;    // masked frame; never consumed downstream

    const int tid = threadIdx.x;
    __shared__ v4f   sxy[512];    // stage-1 out {x.re,x.im,y.re,y.im}, idx t0*32+m
    __shared__ float frf[512];    // staging (x,y interleaved); aliased px/py later

    const int* sf = srcfrm + b * NFRAMES;
    const float* xg = tgt + (size_t)b * T_LEN;
    const float* yg = est + (size_t)b * T_LEN;

    // staging: thread t handles samples t and t+128 (both OLA branches, uniform)
    {
        const int t = tid;
        const int k0 = sf[j];
        const float wa = win[t], wb = win[t + HOP];
        float xv = xg[k0 * HOP + t] * wa;
        float yv = yg[k0 * HOP + t] * wa;
        if (j >= 1) {
            const int km = sf[j - 1];
            xv = fmaf(xg[km * HOP + HOP + t], wb, xv);
            yv = fmaf(yg[km * HOP + HOP + t], wb, yv);
        }
        const int kp = sf[j + 1];
        float xv2 = xg[k0 * HOP + HOP + t] * wb;
        float yv2 = yg[k0 * HOP + HOP + t] * wb;
        xv2 = fmaf(xg[kp * HOP + t], wa, xv2);
        yv2 = fmaf(yg[kp * HOP + t], wa, yv2);
        *(v2f*)&frf[2 * t]         = (v2f){ xv * wa,  yv * wa  };
        *(v2f*)&frf[2 * (t + HOP)] = (v2f){ xv2 * wb, yv2 * wb };
    }
    __syncthreads();

    // ---- Stage 1
    {
        const int m = tid & 15;
        const int g = tid >> 4;            // 0..7 -> t0 in {2g, 2g+1}
        const float ang = -0.19634954084936207f * (float)m;  // -pi/16 * m
        const v2f cksk = { __cosf(ang), __sinf(ang) };
        v2f cs = { 1.f, 0.f };
        v2f xEa = {0,0}, xOa = {0,0}, yEa = {0,0}, yOa = {0,0};
        v2f xEb = {0,0}, xOb = {0,0}, yEb = {0,0}, yOb = {0,0};
        #pragma unroll
        for (int t1 = 0; t1 < 16; ++t1) {
            const v4f vv = *(const v4f*)&frf[4 * (t1 * 8 + g)];  // samples 16t1+2g, +1
            const v2f va = vv.xy, vb = vv.zw;
            if ((t1 & 1) == 0) {
                pk_fma_blo(xEa, cs, va); pk_fma_bhi(yEa, cs, va);
                pk_fma_blo(xEb, cs, vb); pk_fma_bhi(yEb, cs, vb);
            } else {
                pk_fma_blo(xOa, cs, va); pk_fma_bhi(yOa, cs, va);
                pk_fma_blo(xOb, cs, vb); pk_fma_bhi(yOb, cs, vb);
            }
            pk_rot(cs, cksk);
        }
        const int t0a = 2 * g, t0b = 2 * g + 1;
        v2f xs, ys;
        xs = xEa + xOa; ys = yEa + yOa;
        sxy[t0a * 32 + m]      = (v4f){ xs.x, xs.y, ys.x, ys.y };
        xs = xEa - xOa; ys = yEa - yOa;
        sxy[t0a * 32 + m + 16] = (v4f){ xs.x, xs.y, ys.x, ys.y };
        xs = xEb + xOb; ys = yEb + yOb;
        sxy[t0b * 32 + m]      = (v4f){ xs.x, xs.y, ys.x, ys.y };
        xs = xEb - xOb; ys = yEb - yOb;
        sxy[t0b * 32 + m + 16] = (v4f){ xs.x, xs.y, ys.x, ys.y };
    }
    __syncthreads();

    // ---- Stage 2: two bins per thread sharing S reads (k1 and k1+128)
    const int blo = band_lo[NUMBAND];
    const int bhi = band_hi[NUMBAND];
    float* px = frf;            // alias: frf dead after stage 1; NK <= 224
    float* py = frf + 224;
    {
        const int m2 = tid & 31;
        const int p  = tid >> 5;           // 0..3
        const int base = blo & ~31;
        const int k1 = base + m2 + 32 * p;
        const int k2b = k1 + 128;
        const float ang = -0.012271846303085130f * (float)k1;  // -pi/256 * k1
        const float c1 = __cosf(ang), s1 = __sinf(ang);
        const v2f cksk1 = { c1, s1 };
        const v2f cksk2 = { s1, -c1 };     // step1 * (-i)
        v2f cs1 = { 1.f, 0.f }, cs2 = { 1.f, 0.f };
        v2f a1x = {0,0}, a1y = {0,0}, a2x = {0,0}, a2y = {0,0};
        #pragma unroll
        for (int t0 = 0; t0 < 16; ++t0) {
            const v4f sv = sxy[t0 * 32 + m2];
            const v2f sx = sv.xy, sy = sv.zw;
            pk_fma_blo(a1x, cs1, sx); pk_fma_rot(a1x, cs1, sx);
            pk_fma_blo(a1y, cs1, sy); pk_fma_rot(a1y, cs1, sy);
            pk_fma_blo(a2x, cs2, sx); pk_fma_rot(a2x, cs2, sx);
            pk_fma_blo(a2y, cs2, sy); pk_fma_rot(a2y, cs2, sy);
            pk_rot(cs1, cksk1);
            pk_rot(cs2, cksk2);
        }
        if (k1 >= blo && k1 < bhi) {
            px[k1 - blo] = fmaf(a1x.x, a1x.x, a1x.y * a1x.y);
            py[k1 - blo] = fmaf(a1y.x, a1y.x, a1y.y * a1y.y);
        }
        if (k2b < bhi) {                    // k2b >= 128 > blo always
            px[k2b - blo] = fmaf(a2x.x, a2x.x, a2x.y * a2x.y);
            py[k2b - blo] = fmaf(a2y.x, a2y.x, a2y.y * a2y.y);
        }
    }
    __syncthreads();

    // Third-octave band sums -> sqrt(E + EPS)
    if (tid < NUMBAND) {
        float ssum = 0.f;
        const int lo = band_lo[tid], hi = band_hi[tid];
        for (int k = lo; k < hi; ++k) ssum += px[k - blo];
        xtob[((size_t)b * NUMBAND + tid) * NSTFT + j] = sqrtf(ssum + EPSF);
    } else if (tid >= 32 && tid < 32 + NUMBAND) {
        const int band = tid - 32;
        float ssum = 0.f;
        const int lo = band_lo[band], hi = band_hi[band];
        for (int k = lo; k < hi; ++k) ssum += py[k - blo];
        ytob[((size_t)b * NUMBAND + band) * NSTFT + j] = sqrtf(ssum + EPSF);
    }
}

__global__ __launch_bounds__(256)
void k3_corr(const float* __restrict__ xtob, const float* __restrict__ ytob,
             const int* __restrict__ counts, float* __restrict__ acc)
{
    const int bb = blockIdx.y;
    const int b = bb / NUMBAND;
    const int band = bb % NUMBAND;
    const int seg = blockIdx.x * 256 + threadIdx.x;

    int nvalid = counts[b] - N_INTEL;
    if (nvalid < 0) nvalid = 0;
    if (nvalid > NSEG) nvalid = NSEG;

    float d = 0.f;
    if (seg < nvalid) {
        const float* xr = xtob + ((size_t)b * NUMBAND + band) * NSTFT + seg;
        const float* yr = ytob + ((size_t)b * NUMBAND + band) * NSTFT + seg;
        float xv[N_INTEL], yv[N_INTEL];
        float sx2 = 0.f, sy2 = 0.f;
        #pragma unroll
        for (int i = 0; i < N_INTEL; ++i) {
            xv[i] = xr[i]; yv[i] = yr[i];
            sx2 = fmaf(xv[i], xv[i], sx2);
            sy2 = fmaf(yv[i], yv[i], sy2);
        }
        const float nc = sqrtf(sx2) / (sqrtf(sy2) + EPSF);
        float sy = 0.f, sx = 0.f;
        #pragma unroll
        for (int i = 0; i < N_INTEL; ++i) {
            const float yp = fminf(yv[i] * nc, xv[i] * (1.f + CLIP_VAL));
            yv[i] = yp;
            sy += yp; sx += xv[i];
        }
        const float my = sy * (1.f / N_INTEL);
        const float mxm = sx * (1.f / N_INTEL);
        float num = 0.f, dy = 0.f, dx2 = 0.f;
        #pragma unroll
        for (int i = 0; i < N_INTEL; ++i) {
            const float a = yv[i] - my;
            const float c = xv[i] - mxm;
            num = fmaf(a, c, num);
            dy  = fmaf(a, a, dy);
            dx2 = fmaf(c, c, dx2);
        }
        d = num / ((sqrtf(dy) + EPSF) * (sqrtf(dx2) + EPSF));
    }

    #pragma unroll
    for (int o = 32; o > 0; o >>= 1) d += __shfl_down(d, o, 64);
    __shared__ float wsum[4];
    const int lane = threadIdx.x & 63, wid = threadIdx.x >> 6;
    if (lane == 0) wsum[wid] = d;
    __syncthreads();
    if (threadIdx.x == 0) {
        atomicAdd(&acc[b], wsum[0] + wsum[1] + wsum[2] + wsum[3]);
    }
}

__global__ void k4_final(const float* __restrict__ acc, const int* __restrict__ counts,
                         float* __restrict__ out)
{
    const int b = threadIdx.x;
    if (b < NB) {
        int nvalid = counts[b] - N_INTEL;
        if (nvalid < 0) nvalid = 0;
        if (nvalid > NSEG) nvalid = NSEG;
        out[b] = -(acc[b] * (1.f / NUMBAND)) / ((float)nvalid + EPSF);
    }
}

extern "C" void kernel_launch(void* const* d_in, const int* in_sizes, int n_in,
                              void* d_out, int out_size, void* d_ws, size_t ws_size,
                              hipStream_t stream) {
    (void)in_sizes; (void)n_in; (void)out_size; (void)ws_size;
    const float* est = (const float*)d_in[0];
    const float* tgt = (const float*)d_in[1];
    const float* win = (const float*)d_in[2];
    const float* obm = (const float*)d_in[3];
    float* out = (float*)d_out;

    char* ws = (char*)d_ws;
    int*   counts  = (int*)(ws + WS_COUNTS);
    int*   band_lo = (int*)(ws + WS_BANDLO);
    int*   band_hi = (int*)(ws + WS_BANDHI);
    float* acc     = (float*)(ws + WS_ACC);
    int*   srcfrm  = (int*)(ws + WS_SRCFRM);
    float* xtob    = (float*)(ws + WS_XTOB);
    float* ytob    = (float*)(ws + WS_YTOB);
    float* nrm     = xtob;   // scratch alias: consumed by k1b before k2 writes xtob

    k1a_norms<<<dim3(NB, 20), dim3(256), 0, stream>>>(tgt, win, nrm);
    k1b_scan<<<dim3(NB), dim3(256), 0, stream>>>(nrm, obm, counts, srcfrm,
                                                 band_lo, band_hi, acc);
    k2_stft_tob<<<dim3(NSTFT, NB), dim3(128), 0, stream>>>(est, tgt, win, counts, srcfrm,
                                                           band_lo, band_hi, xtob, ytob);
    k3_corr<<<dim3((NSEG + 255) / 256, NB * NUMBAND), dim3(256), 0, stream>>>(xtob, ytob,
                                                                              counts, acc);
    k4_final<<<1, NB, 0, stream>>>(acc, counts, out);
}

// Round 5
// 249.820 us; speedup vs baseline: 3.6941x; 1.0852x over previous
//
#include <hip/hip_runtime.h>
#include <math.h>

#define EPSF 1e-8f
#define WIN_LEN 256
#define HOP 128
#define NBINS 257          // rfft bins of 512
#define NUMBAND 15
#define NFRAMES 2499       // (320000-256)/128+1
#define NSTFT 2498         // NFRAMES-1
#define N_INTEL 30
#define NSEG 2469          // NSTFT - N_INTEL + 1
#define NB 32              // batch
#define T_LEN 320000
#define CLIP_VAL 5.623413251903491f   // 10^(15/20)
#define NRM_STRIDE 2560

typedef float v2f __attribute__((ext_vector_type(2)));
typedef float v4f __attribute__((ext_vector_type(4)));

// ---- packed fp32 helpers (VOP3P) ----
// d += a * bcast(b.lo)
__device__ __forceinline__ void pk_fma_blo(v2f& d, v2f a, v2f b) {
    asm("v_pk_fma_f32 %0, %1, %2, %0 op_sel:[0,0,0] op_sel_hi:[1,0,1]"
        : "+v"(d) : "v"(a), "v"(b));
}
// d += a * bcast(b.hi)
__device__ __forceinline__ void pk_fma_bhi(v2f& d, v2f a, v2f b) {
    asm("v_pk_fma_f32 %0, %1, %2, %0 op_sel:[0,1,0] op_sel_hi:[1,1,1]"
        : "+v"(d) : "v"(a), "v"(b));
}
// d += (-a.hi*b.hi, a.lo*b.hi)   (complex rotate-accumulate, imag term)
__device__ __forceinline__ void pk_fma_rot(v2f& d, v2f a, v2f b) {
    asm("v_pk_fma_f32 %0, %1, %2, %0 op_sel:[1,1,0] op_sel_hi:[0,1,1] neg_lo:[1,0,0]"
        : "+v"(d) : "v"(a), "v"(b));
}
// cs = cs * (ck + i sk), cksk = (ck, sk)
__device__ __forceinline__ void pk_rot(v2f& cs, v2f cksk) {
    v2f t;
    asm("v_pk_mul_f32 %0, %1, %2 op_sel:[0,0] op_sel_hi:[1,0]"
        : "=v"(t) : "v"(cs), "v"(cksk));                 // (c*ck, s*ck)
    asm("v_pk_fma_f32 %0, %0, %1, %2 op_sel:[1,1,0] op_sel_hi:[0,1,1] neg_lo:[1,0,0]"
        : "+v"(cs) : "v"(cksk), "v"(t));                 // (c*ck - s*sk, s*ck + c*sk)
}

// ---- workspace layout (bytes) ----
#define WS_COUNTS   0
#define WS_BANDLO   512
#define WS_BANDHI   768
#define WS_ACC      1024
#define WS_SRCFRM   2048
#define WS_XTOB     324096     // nrm scratch aliases this region (consumed before k2)
#define WS_YTOB     5120512

__global__ __launch_bounds__(256)
void k1a_norms(const float* __restrict__ tgt, const float* __restrict__ win,
               float* __restrict__ nrm)
{
    const int b = blockIdx.x;
    const int blk = blockIdx.y;
    const int tid = threadIdx.x;
    const int frame = blk * 128 + (tid >> 1);
    const int half = tid & 1;
    if (frame >= NFRAMES) return;   // partner lane exits too (same frame)

    const float* xp = tgt + (size_t)b * T_LEN + (size_t)(frame + half) * HOP;
    const float* wp = win + half * HOP;
    float s = 0.f;
    #pragma unroll 8
    for (int t = 0; t < HOP; t += 4) {
        const float4 xv = *(const float4*)(xp + t);
        const float4 wv = *(const float4*)(wp + t);
        float v0 = xv.x * wv.x, v1 = xv.y * wv.y, v2 = xv.z * wv.z, v3 = xv.w * wv.w;
        s = fmaf(v0, v0, s); s = fmaf(v1, v1, s);
        s = fmaf(v2, v2, s); s = fmaf(v3, v3, s);
    }
    s += __shfl_xor(s, 1, 64);
    if (half == 0) nrm[(size_t)b * NRM_STRIDE + frame] = sqrtf(s);
}

__global__ __launch_bounds__(256)
void k1b_scan(const float* __restrict__ nrm, const float* __restrict__ obm,
              int* __restrict__ counts, int* __restrict__ srcfrm,
              int* __restrict__ band_lo, int* __restrict__ band_hi,
              float* __restrict__ acc)
{
    const int b = blockIdx.x;
    const int tid = threadIdx.x;
    __shared__ float nr[NFRAMES];
    __shared__ float red[256];
    __shared__ int   sc[256];

    const float* np_ = nrm + (size_t)b * NRM_STRIDE;
    for (int f = tid; f < NFRAMES; f += 256) nr[f] = np_[f];
    __syncthreads();

    float mx = 0.f;
    for (int f = tid; f < NFRAMES; f += 256) mx = fmaxf(mx, nr[f]);
    red[tid] = mx;
    __syncthreads();
    for (int s = 128; s > 0; s >>= 1) {
        if (tid < s) red[tid] = fmaxf(red[tid], red[tid + s]);
        __syncthreads();
    }
    const float thr = (red[0] + EPSF) * 0.01f;   // 10^(-40/20)

    const int c0 = tid * 10;
    const int c1 = (c0 + 10 < NFRAMES) ? c0 + 10 : NFRAMES;
    int lc = 0;
    for (int f = c0; f < c1; ++f) if (nr[f] + EPSF > thr) ++lc;
    sc[tid] = lc;
    __syncthreads();
    // Hillis-Steele inclusive scan over 256 partial counts
    #pragma unroll
    for (int off = 1; off < 256; off <<= 1) {
        int u = (tid >= off) ? sc[tid - off] : 0;
        __syncthreads();
        sc[tid] += u;
        __syncthreads();
    }
    if (tid == 0) {
        counts[b] = sc[255];
        acc[b] = 0.f;   // self-init accumulator every launch
    }
    int pos = sc[tid] - lc;   // exclusive prefix
    int* sf = srcfrm + b * NFRAMES;
    for (int f = c0; f < c1; ++f) if (nr[f] + EPSF > thr) sf[pos++] = f;

    if (b == 0 && tid < NUMBAND) {
        int lo = -1, hi = 0;
        for (int k = 0; k < NBINS; ++k) {
            if (obm[tid * NBINS + k] != 0.f) { if (lo < 0) lo = k; hi = k + 1; }
        }
        band_lo[tid] = (lo < 0) ? 0 : lo;
        band_hi[tid] = hi;
    }
    __syncthreads();
    if (b == 0 && tid == 0) {
        int lo = NBINS, hi = 0;
        for (int i = 0; i < NUMBAND; ++i) {
            if (band_lo[i] < lo) lo = band_lo[i];
            if (band_hi[i] > hi) hi = band_hi[i];
        }
        band_lo[NUMBAND] = lo;
        band_hi[NUMBAND] = hi;
    }
}

// Two-stage factorized DFT (512 = 32 x 16), 128 threads/block.
// Stage 1: S[t0][m] = sum_{t1<16} x[16*t1+t0] * W32^{m*t1}; thread = (m<16, g<8)
//   computes m and m+16 via parity split: W32^{(m+16)t1} = W32^{m t1} * (-1)^t1.
// Stage 2: thread = (m2<32, p<4), bins k1 = base+m2+32p and k1+128 via mod-4
//   partial sums: T_r = sum_{t0=4q+r} W512^{k1 t0} S[t0];
//   X[k1] = T0+T1+T2+T3;  X[k1+128] = T0 - i T1 - T2 + i T3 = (T0-T2) - i(T1-T3).
__global__ __launch_bounds__(128)
void k2_stft_tob(const float* __restrict__ est, const float* __restrict__ tgt,
                 const float* __restrict__ win,
                 const int* __restrict__ counts, const int* __restrict__ srcfrm,
                 const int* __restrict__ band_lo, const int* __restrict__ band_hi,
                 float* __restrict__ xtob, float* __restrict__ ytob)
{
    // bijective XCD-chunked remap: consecutive j share an XCD (kills xtob
    // write false-sharing across XCD L2s; improves signal-read L2 reuse)
    const int lin = blockIdx.x;
    const int xcd = lin & 7, cidx = lin >> 3;
    const int q = NSTFT >> 3, r = NSTFT & 7;
    const int j = (xcd < r ? xcd * (q + 1) : r * (q + 1) + (xcd - r) * q) + cidx;

    const int b = blockIdx.y;
    const int cntb = counts[b];
    if (j >= cntb - 1) return;    // masked frame; never consumed downstream

    const int tid = threadIdx.x;
    __shared__ v4f   sxy[512];    // stage-1 out {x.re,x.im,y.re,y.im}, idx t0*32+m
    __shared__ float frf[512];    // staging (x,y interleaved); aliased px/py later

    const int* sf = srcfrm + b * NFRAMES;
    const float* xg = tgt + (size_t)b * T_LEN;
    const float* yg = est + (size_t)b * T_LEN;

    // staging: thread tid builds samples (2 tid, 2 tid+1); wave-uniform branches
    {
        const int t2 = 2 * tid;
        const int k0 = sf[j];
        const v2f wa = *(const v2f*)&win[t2];
        v2f xv, yv;
        if (tid < 64) {                      // samples < HOP
            xv = *(const v2f*)&xg[k0 * HOP + t2] * wa;
            yv = *(const v2f*)&yg[k0 * HOP + t2] * wa;
            if (j >= 1) {
                const int km = sf[j - 1];
                const v2f wb = *(const v2f*)&win[HOP + t2];
                xv += *(const v2f*)&xg[km * HOP + HOP + t2] * wb;
                yv += *(const v2f*)&yg[km * HOP + HOP + t2] * wb;
            }
        } else {                             // samples >= HOP
            const int kp = sf[j + 1];
            const v2f wb = *(const v2f*)&win[t2 - HOP];
            xv = *(const v2f*)&xg[k0 * HOP + t2] * wa
               + *(const v2f*)&xg[kp * HOP + t2 - HOP] * wb;
            yv = *(const v2f*)&yg[k0 * HOP + t2] * wa
               + *(const v2f*)&yg[kp * HOP + t2 - HOP] * wb;
        }
        const v4f st = { xv.x * wa.x, yv.x * wa.x, xv.y * wa.y, yv.y * wa.y };
        *(v4f*)&frf[4 * tid] = st;
    }
    __syncthreads();

    // ---- Stage 1
    {
        const int m = tid & 15;
        const int g = tid >> 4;            // 0..7 -> t0 in {2g, 2g+1}
        const float ang = -0.19634954084936207f * (float)m;  // -pi/16 * m
        const v2f cksk = { __cosf(ang), __sinf(ang) };
        v2f cs = { 1.f, 0.f };
        v2f xEa = {0,0}, xOa = {0,0}, yEa = {0,0}, yOa = {0,0};
        v2f xEb = {0,0}, xOb = {0,0}, yEb = {0,0}, yOb = {0,0};
        #pragma unroll
        for (int t1 = 0; t1 < 16; ++t1) {
            const v4f vv = *(const v4f*)&frf[4 * (t1 * 8 + g)];  // samples 16t1+2g, +1
            const v2f va = vv.xy, vb = vv.zw;
            if ((t1 & 1) == 0) {
                pk_fma_blo(xEa, cs, va); pk_fma_bhi(yEa, cs, va);
                pk_fma_blo(xEb, cs, vb); pk_fma_bhi(yEb, cs, vb);
            } else {
                pk_fma_blo(xOa, cs, va); pk_fma_bhi(yOa, cs, va);
                pk_fma_blo(xOb, cs, vb); pk_fma_bhi(yOb, cs, vb);
            }
            pk_rot(cs, cksk);
        }
        const int t0a = 2 * g, t0b = 2 * g + 1;
        v2f xs, ys;
        xs = xEa + xOa; ys = yEa + yOa;
        sxy[t0a * 32 + m]      = (v4f){ xs.x, xs.y, ys.x, ys.y };
        xs = xEa - xOa; ys = yEa - yOa;
        sxy[t0a * 32 + m + 16] = (v4f){ xs.x, xs.y, ys.x, ys.y };
        xs = xEb + xOb; ys = yEb + yOb;
        sxy[t0b * 32 + m]      = (v4f){ xs.x, xs.y, ys.x, ys.y };
        xs = xEb - xOb; ys = yEb - yOb;
        sxy[t0b * 32 + m + 16] = (v4f){ xs.x, xs.y, ys.x, ys.y };
    }
    __syncthreads();

    // ---- Stage 2: two bins per thread via mod-4 partial sums (one chain)
    const int blo = band_lo[NUMBAND];
    const int bhi = band_hi[NUMBAND];
    float* px = frf;            // alias: frf dead after stage 1; bins <= 224
    float* py = frf + 224;
    {
        const int m2 = tid & 31;
        const int p  = tid >> 5;           // 0..3
        const int base = blo & ~31;
        const int k1 = base + m2 + 32 * p;
        const int k2b = k1 + 128;
        const float ang = -0.012271846303085130f * (float)k1;  // -pi/256 * k1
        const v2f cksk = { __cosf(ang), __sinf(ang) };
        v2f cs = { 1.f, 0.f };
        v2f Tx0 = {0,0}, Tx1 = {0,0}, Tx2 = {0,0}, Tx3 = {0,0};
        v2f Ty0 = {0,0}, Ty1 = {0,0}, Ty2 = {0,0}, Ty3 = {0,0};
        #pragma unroll
        for (int t0 = 0; t0 < 16; ++t0) {
            const v4f sv = sxy[t0 * 32 + m2];
            const v2f sx = sv.xy, sy = sv.zw;
            if ((t0 & 3) == 0)      { pk_fma_blo(Tx0, cs, sx); pk_fma_rot(Tx0, cs, sx);
                                      pk_fma_blo(Ty0, cs, sy); pk_fma_rot(Ty0, cs, sy); }
            else if ((t0 & 3) == 1) { pk_fma_blo(Tx1, cs, sx); pk_fma_rot(Tx1, cs, sx);
                                      pk_fma_blo(Ty1, cs, sy); pk_fma_rot(Ty1, cs, sy); }
            else if ((t0 & 3) == 2) { pk_fma_blo(Tx2, cs, sx); pk_fma_rot(Tx2, cs, sx);
                                      pk_fma_blo(Ty2, cs, sy); pk_fma_rot(Ty2, cs, sy); }
            else                    { pk_fma_blo(Tx3, cs, sx); pk_fma_rot(Tx3, cs, sx);
                                      pk_fma_blo(Ty3, cs, sy); pk_fma_rot(Ty3, cs, sy); }
            pk_rot(cs, cksk);
        }
        // combine: X1 = T0+T1+T2+T3 ; X2 = (T0-T2) - i (T1-T3)
        const v2f Ax = Tx0 + Tx2, Bx = Tx0 - Tx2, Cx = Tx1 + Tx3, Dx = Tx1 - Tx3;
        const v2f Ay = Ty0 + Ty2, By = Ty0 - Ty2, Cy = Ty1 + Ty3, Dy = Ty1 - Ty3;
        const v2f X1 = Ax + Cx;
        const v2f Y1 = Ay + Cy;
        const v2f X2 = { Bx.x + Dx.y, Bx.y - Dx.x };   // B - i*D
        const v2f Y2 = { By.x + Dy.y, By.y - Dy.x };
        if (k1 >= blo && k1 < bhi) {
            px[k1 - blo] = fmaf(X1.x, X1.x, X1.y * X1.y);
            py[k1 - blo] = fmaf(Y1.x, Y1.x, Y1.y * Y1.y);
        }
        if (k2b < bhi) {                    // k2b >= 128 > blo always
            px[k2b - blo] = fmaf(X2.x, X2.x, X2.y * X2.y);
            py[k2b - blo] = fmaf(Y2.x, Y2.x, Y2.y * Y2.y);
        }
    }
    __syncthreads();

    // Third-octave band sums -> sqrt(E + EPS)
    if (tid < NUMBAND) {
        float ssum = 0.f;
        const int lo = band_lo[tid], hi = band_hi[tid];
        for (int k = lo; k < hi; ++k) ssum += px[k - blo];
        xtob[((size_t)b * NUMBAND + tid) * NSTFT + j] = sqrtf(ssum + EPSF);
    } else if (tid >= 32 && tid < 32 + NUMBAND) {
        const int band = tid - 32;
        float ssum = 0.f;
        const int lo = band_lo[band], hi = band_hi[band];
        for (int k = lo; k < hi; ++k) ssum += py[k - blo];
        ytob[((size_t)b * NUMBAND + band) * NSTFT + j] = sqrtf(ssum + EPSF);
    }
}

__global__ __launch_bounds__(256)
void k3_corr(const float* __restrict__ xtob, const float* __restrict__ ytob,
             const int* __restrict__ counts, float* __restrict__ acc)
{
    const int bb = blockIdx.y;
    const int b = bb / NUMBAND;
    const int band = bb % NUMBAND;
    const int s_base = blockIdx.x * 256;
    const int tid = threadIdx.x;
    const int seg = s_base + tid;

    __shared__ float lx[256 + N_INTEL - 1], ly[256 + N_INTEL - 1];
    const float* xr = xtob + ((size_t)b * NUMBAND + band) * NSTFT;
    const float* yr = ytob + ((size_t)b * NUMBAND + band) * NSTFT;
    for (int i = tid; i < 256 + N_INTEL - 1; i += 256) {
        const int g = s_base + i;
        float vx = 0.f, vy = 0.f;
        if (g < NSTFT) { vx = xr[g]; vy = yr[g]; }
        lx[i] = vx; ly[i] = vy;
    }
    __syncthreads();

    int nvalid = counts[b] - N_INTEL;
    if (nvalid < 0) nvalid = 0;
    if (nvalid > NSEG) nvalid = NSEG;

    float d = 0.f;
    if (seg < nvalid) {
        float xv[N_INTEL], yv[N_INTEL];
        float sx2 = 0.f, sy2 = 0.f;
        #pragma unroll
        for (int i = 0; i < N_INTEL; ++i) {
            xv[i] = lx[tid + i]; yv[i] = ly[tid + i];
            sx2 = fmaf(xv[i], xv[i], sx2);
            sy2 = fmaf(yv[i], yv[i], sy2);
        }
        const float nc = sqrtf(sx2) / (sqrtf(sy2) + EPSF);
        float sy = 0.f, sx = 0.f;
        #pragma unroll
        for (int i = 0; i < N_INTEL; ++i) {
            const float yp = fminf(yv[i] * nc, xv[i] * (1.f + CLIP_VAL));
            yv[i] = yp;
            sy += yp; sx += xv[i];
        }
        const float my = sy * (1.f / N_INTEL);
        const float mxm = sx * (1.f / N_INTEL);
        float num = 0.f, dy = 0.f, dx2 = 0.f;
        #pragma unroll
        for (int i = 0; i < N_INTEL; ++i) {
            const float a = yv[i] - my;
            const float c = xv[i] - mxm;
            num = fmaf(a, c, num);
            dy  = fmaf(a, a, dy);
            dx2 = fmaf(c, c, dx2);
        }
        d = num / ((sqrtf(dy) + EPSF) * (sqrtf(dx2) + EPSF));
    }

    #pragma unroll
    for (int o = 32; o > 0; o >>= 1) d += __shfl_down(d, o, 64);
    __shared__ float wsum[4];
    const int lane = threadIdx.x & 63, wid = threadIdx.x >> 6;
    if (lane == 0) wsum[wid] = d;
    __syncthreads();
    if (threadIdx.x == 0) {
        atomicAdd(&acc[b], wsum[0] + wsum[1] + wsum[2] + wsum[3]);
    }
}

__global__ void k4_final(const float* __restrict__ acc, const int* __restrict__ counts,
                         float* __restrict__ out)
{
    const int b = threadIdx.x;
    if (b < NB) {
        int nvalid = counts[b] - N_INTEL;
        if (nvalid < 0) nvalid = 0;
        if (nvalid > NSEG) nvalid = NSEG;
        out[b] = -(acc[b] * (1.f / NUMBAND)) / ((float)nvalid + EPSF);
    }
}

extern "C" void kernel_launch(void* const* d_in, const int* in_sizes, int n_in,
                              void* d_out, int out_size, void* d_ws, size_t ws_size,
                              hipStream_t stream) {
    (void)in_sizes; (void)n_in; (void)out_size; (void)ws_size;
    const float* est = (const float*)d_in[0];
    const float* tgt = (const float*)d_in[1];
    const float* win = (const float*)d_in[2];
    const float* obm = (const float*)d_in[3];
    float* out = (float*)d_out;

    char* ws = (char*)d_ws;
    int*   counts  = (int*)(ws + WS_COUNTS);
    int*   band_lo = (int*)(ws + WS_BANDLO);
    int*   band_hi = (int*)(ws + WS_BANDHI);
    float* acc     = (float*)(ws + WS_ACC);
    int*   srcfrm  = (int*)(ws + WS_SRCFRM);
    float* xtob    = (float*)(ws + WS_XTOB);
    float* ytob    = (float*)(ws + WS_YTOB);
    float* nrm     = xtob;   // scratch alias: consumed by k1b before k2 writes xtob

    k1a_norms<<<dim3(NB, 20), dim3(256), 0, stream>>>(tgt, win, nrm);
    k1b_scan<<<dim3(NB), dim3(256), 0, stream>>>(nrm, obm, counts, srcfrm,
                                                 band_lo, band_hi, acc);
    k2_stft_tob<<<dim3(NSTFT, NB), dim3(128), 0, stream>>>(est, tgt, win, counts, srcfrm,
                                                           band_lo, band_hi, xtob, ytob);
    k3_corr<<<dim3((NSEG + 255) / 256, NB * NUMBAND), dim3(256), 0, stream>>>(xtob, ytob,
                                                                              counts, acc);
    k4_final<<<1, NB, 0, stream>>>(acc, counts, out);
}

// Round 6
// 198.149 us; speedup vs baseline: 4.6573x; 1.2608x over previous
//
#include <hip/hip_runtime.h>
#include <math.h>

#define EPSF 1e-8f
#define WIN_LEN 256
#define HOP 128
#define NBINS 257          // rfft bins of 512
#define NUMBAND 15
#define NFRAMES 2499       // (320000-256)/128+1
#define NSTFT 2498         // NFRAMES-1
#define N_INTEL 30
#define NSEG 2469          // NSTFT - N_INTEL + 1
#define NB 32              // batch
#define T_LEN 320000
#define CLIP_VAL 5.623413251903491f   // 10^(15/20)
#define NHALF 2500         // half-frames (T_LEN/HOP)
#define AB_STRIDE 2560

typedef float v2f __attribute__((ext_vector_type(2)));
typedef float v4f __attribute__((ext_vector_type(4)));

// ---- packed fp32 helpers (VOP3P) ----
// d += a * bcast(b.lo)
__device__ __forceinline__ void pk_fma_blo(v2f& d, v2f a, v2f b) {
    asm("v_pk_fma_f32 %0, %1, %2, %0 op_sel:[0,0,0] op_sel_hi:[1,0,1]"
        : "+v"(d) : "v"(a), "v"(b));
}
// d += a * bcast(b.hi)
__device__ __forceinline__ void pk_fma_bhi(v2f& d, v2f a, v2f b) {
    asm("v_pk_fma_f32 %0, %1, %2, %0 op_sel:[0,1,0] op_sel_hi:[1,1,1]"
        : "+v"(d) : "v"(a), "v"(b));
}
// d += (-a.hi*b.hi, a.lo*b.hi)   (complex rotate-accumulate, imag term)
__device__ __forceinline__ void pk_fma_rot(v2f& d, v2f a, v2f b) {
    asm("v_pk_fma_f32 %0, %1, %2, %0 op_sel:[1,1,0] op_sel_hi:[0,1,1] neg_lo:[1,0,0]"
        : "+v"(d) : "v"(a), "v"(b));
}
// cs = cs * (ck + i sk), cksk = (ck, sk)
__device__ __forceinline__ void pk_rot(v2f& cs, v2f cksk) {
    v2f t;
    asm("v_pk_mul_f32 %0, %1, %2 op_sel:[0,0] op_sel_hi:[1,0]"
        : "=v"(t) : "v"(cs), "v"(cksk));                 // (c*ck, s*ck)
    asm("v_pk_fma_f32 %0, %0, %1, %2 op_sel:[1,1,0] op_sel_hi:[0,1,1] neg_lo:[1,0,0]"
        : "+v"(cs) : "v"(cksk), "v"(t));                 // (c*ck - s*sk, s*ck + c*sk)
}

// ---- workspace layout (bytes) ----
#define WS_COUNTS   0
#define WS_BANDLO   512
#define WS_BANDHI   768
#define WS_ACC      1024
#define WS_SRCFRM   2048
#define WS_XTOB     324096     // ab scratch aliases this region (consumed before k2)
#define WS_YTOB     5120512

// Per-half-frame windowed energy partials: A[h] (low window), B[h] (high window).
// norm^2[f] = A[f] + B[f+1]. Each sample read exactly once.
__global__ __launch_bounds__(256)
void k1a_ab(const float* __restrict__ tgt, const float* __restrict__ win,
            float2* __restrict__ ab)
{
    const int b = blockIdx.x;
    const int h = blockIdx.y * 256 + threadIdx.x;
    if (h >= NHALF) return;
    const float* xp = tgt + (size_t)b * T_LEN + (size_t)h * HOP;
    float sa = 0.f, sb = 0.f;
    #pragma unroll 4
    for (int u = 0; u < HOP; u += 4) {
        const float4 xv = *(const float4*)(xp + u);
        const float4 wl = *(const float4*)(win + u);
        const float4 wh = *(const float4*)(win + HOP + u);
        float a;
        a = xv.x * wl.x; sa = fmaf(a, a, sa);
        a = xv.y * wl.y; sa = fmaf(a, a, sa);
        a = xv.z * wl.z; sa = fmaf(a, a, sa);
        a = xv.w * wl.w; sa = fmaf(a, a, sa);
        a = xv.x * wh.x; sb = fmaf(a, a, sb);
        a = xv.y * wh.y; sb = fmaf(a, a, sb);
        a = xv.z * wh.z; sb = fmaf(a, a, sb);
        a = xv.w * wh.w; sb = fmaf(a, a, sb);
    }
    ab[(size_t)b * AB_STRIDE + h] = make_float2(sa, sb);
}

__global__ __launch_bounds__(256)
void k1b_scan(const float2* __restrict__ ab, const float* __restrict__ obm,
              int* __restrict__ counts, int* __restrict__ srcfrm,
              int* __restrict__ band_lo, int* __restrict__ band_hi,
              float* __restrict__ acc)
{
    const int b = blockIdx.x;
    const int tid = threadIdx.x;
    __shared__ float nr[NFRAMES];
    __shared__ float red[256];
    __shared__ int   sc[256];

    const float2* abp = ab + (size_t)b * AB_STRIDE;
    for (int f = tid; f < NFRAMES; f += 256) {
        const float2 p0 = abp[f];
        const float2 p1 = abp[f + 1];
        nr[f] = sqrtf(p0.x + p1.y);
    }
    __syncthreads();

    float mx = 0.f;
    for (int f = tid; f < NFRAMES; f += 256) mx = fmaxf(mx, nr[f]);
    red[tid] = mx;
    __syncthreads();
    for (int s = 128; s > 0; s >>= 1) {
        if (tid < s) red[tid] = fmaxf(red[tid], red[tid + s]);
        __syncthreads();
    }
    const float thr = (red[0] + EPSF) * 0.01f;   // 10^(-40/20)

    const int c0 = tid * 10;
    const int c1 = (c0 + 10 < NFRAMES) ? c0 + 10 : NFRAMES;
    int lc = 0;
    for (int f = c0; f < c1; ++f) if (nr[f] + EPSF > thr) ++lc;
    sc[tid] = lc;
    __syncthreads();
    // Hillis-Steele inclusive scan over 256 partial counts
    #pragma unroll
    for (int off = 1; off < 256; off <<= 1) {
        int u = (tid >= off) ? sc[tid - off] : 0;
        __syncthreads();
        sc[tid] += u;
        __syncthreads();
    }
    if (tid == 0) {
        counts[b] = sc[255];
        acc[b] = 0.f;   // self-init accumulator every launch
    }
    int pos = sc[tid] - lc;   // exclusive prefix
    int* sf = srcfrm + b * NFRAMES;
    for (int f = c0; f < c1; ++f) if (nr[f] + EPSF > thr) sf[pos++] = f;

    if (b == 0 && tid < NUMBAND) {
        int lo = -1, hi = 0;
        for (int k = 0; k < NBINS; ++k) {
            if (obm[tid * NBINS + k] != 0.f) { if (lo < 0) lo = k; hi = k + 1; }
        }
        band_lo[tid] = (lo < 0) ? 0 : lo;
        band_hi[tid] = hi;
    }
    __syncthreads();
    if (b == 0 && tid == 0) {
        int lo = NBINS, hi = 0;
        for (int i = 0; i < NUMBAND; ++i) {
            if (band_lo[i] < lo) lo = band_lo[i];
            if (band_hi[i] > hi) hi = band_hi[i];
        }
        band_lo[NUMBAND] = lo;
        band_hi[NUMBAND] = hi;
    }
}

// Two-stage factorized DFT (512 = 32 x 16), 128 threads/block.
// Stage 1 (radix-4 m-split): thread = (m<8, c<16) computes S[c][m+8j], j<4,
//   from mod-4 partial sums T_r = sum_{t1≡r(4)} x[16t1+c] W32^{m t1}:
//   S[m]=A+C, S[m+16]=A-C, S[m+8]=B-iD, S[m+24]=B+iD
//   with A=T0+T2, B=T0-T2, C=T1+T3, D=T1-T3.
// Stage 2: thread = (m2<32, p<4), bins k1 = base+tid and k1+128 via mod-4
//   partial sums (same butterfly identity over t0).
__global__ __launch_bounds__(128)
void k2_stft_tob(const float* __restrict__ est, const float* __restrict__ tgt,
                 const float* __restrict__ win,
                 const int* __restrict__ counts, const int* __restrict__ srcfrm,
                 const int* __restrict__ band_lo, const int* __restrict__ band_hi,
                 float* __restrict__ xtob, float* __restrict__ ytob)
{
    // bijective XCD-chunked remap (L2 locality for reads + tob writes)
    const int lin = blockIdx.x;
    const int xcd = lin & 7, cidx = lin >> 3;
    const int q = NSTFT >> 3, r = NSTFT & 7;
    const int j = (xcd < r ? xcd * (q + 1) : r * (q + 1) + (xcd - r) * q) + cidx;

    const int b = blockIdx.y;
    const int cntb = counts[b];
    if (j >= cntb - 1) return;    // masked frame; never consumed downstream

    const int tid = threadIdx.x;
    __shared__ v4f   sxy[512];    // stage-1 out {x.re,x.im,y.re,y.im}, idx t0*32+m
    __shared__ float frf[512];    // staging (x,y interleaved); aliased px/py later

    const int* sf = srcfrm + b * NFRAMES;
    const float* xg = tgt + (size_t)b * T_LEN;
    const float* yg = est + (size_t)b * T_LEN;

    // staging: thread tid builds samples (2 tid, 2 tid+1); wave-uniform branches
    {
        const int t2 = 2 * tid;
        const int k0 = sf[j];
        const v2f wa = *(const v2f*)&win[t2];
        v2f xv, yv;
        if (tid < 64) {                      // samples < HOP
            xv = *(const v2f*)&xg[k0 * HOP + t2] * wa;
            yv = *(const v2f*)&yg[k0 * HOP + t2] * wa;
            if (j >= 1) {
                const int km = sf[j - 1];
                const v2f wb = *(const v2f*)&win[HOP + t2];
                xv += *(const v2f*)&xg[km * HOP + HOP + t2] * wb;
                yv += *(const v2f*)&yg[km * HOP + HOP + t2] * wb;
            }
        } else {                             // samples >= HOP
            const int kp = sf[j + 1];
            const v2f wb = *(const v2f*)&win[t2 - HOP];
            xv = *(const v2f*)&xg[k0 * HOP + t2] * wa
               + *(const v2f*)&xg[kp * HOP + t2 - HOP] * wb;
            yv = *(const v2f*)&yg[k0 * HOP + t2] * wa
               + *(const v2f*)&yg[kp * HOP + t2 - HOP] * wb;
        }
        const v4f st = { xv.x * wa.x, yv.x * wa.x, xv.y * wa.y, yv.y * wa.y };
        *(v4f*)&frf[4 * tid] = st;
    }
    __syncthreads();

    // ---- Stage 1 (radix-4 m-split, one column per thread)
    {
        const int m = tid & 7;
        const int c = tid >> 3;            // column t0 = c, 0..15
        const float ang = -0.19634954084936207f * (float)m;  // -pi/16 * m
        const v2f cksk = { __cosf(ang), __sinf(ang) };
        v2f cs = { 1.f, 0.f };
        v2f Tx0 = {0,0}, Tx1 = {0,0}, Tx2 = {0,0}, Tx3 = {0,0};
        v2f Ty0 = {0,0}, Ty1 = {0,0}, Ty2 = {0,0}, Ty3 = {0,0};
        #pragma unroll
        for (int t1 = 0; t1 < 16; ++t1) {
            const v2f va = *(const v2f*)&frf[2 * (t1 * 16 + c)];
            if ((t1 & 3) == 0)      { pk_fma_blo(Tx0, cs, va); pk_fma_bhi(Ty0, cs, va); }
            else if ((t1 & 3) == 1) { pk_fma_blo(Tx1, cs, va); pk_fma_bhi(Ty1, cs, va); }
            else if ((t1 & 3) == 2) { pk_fma_blo(Tx2, cs, va); pk_fma_bhi(Ty2, cs, va); }
            else                    { pk_fma_blo(Tx3, cs, va); pk_fma_bhi(Ty3, cs, va); }
            pk_rot(cs, cksk);
        }
        const v2f Ax = Tx0 + Tx2, Bx = Tx0 - Tx2, Cx = Tx1 + Tx3, Dx = Tx1 - Tx3;
        const v2f Ay = Ty0 + Ty2, By = Ty0 - Ty2, Cy = Ty1 + Ty3, Dy = Ty1 - Ty3;
        const v2f S0x = Ax + Cx, S2x = Ax - Cx;
        const v2f S0y = Ay + Cy, S2y = Ay - Cy;
        const v2f S1x = { Bx.x + Dx.y, Bx.y - Dx.x };   // B - iD
        const v2f S1y = { By.x + Dy.y, By.y - Dy.x };
        const v2f S3x = { Bx.x - Dx.y, Bx.y + Dx.x };   // B + iD
        const v2f S3y = { By.x - Dy.y, By.y + Dy.x };
        sxy[c * 32 + m]      = (v4f){ S0x.x, S0x.y, S0y.x, S0y.y };
        sxy[c * 32 + m + 8]  = (v4f){ S1x.x, S1x.y, S1y.x, S1y.y };
        sxy[c * 32 + m + 16] = (v4f){ S2x.x, S2x.y, S2y.x, S2y.y };
        sxy[c * 32 + m + 24] = (v4f){ S3x.x, S3x.y, S3y.x, S3y.y };
    }
    __syncthreads();

    // ---- Stage 2: two bins per thread via mod-4 partial sums (one chain)
    const int blo = band_lo[NUMBAND];
    const int bhi = band_hi[NUMBAND];
    float* px = frf;            // alias: frf dead after stage 1; bins <= 224
    float* py = frf + 224;
    {
        const int m2 = tid & 31;
        const int base = blo & ~31;
        const int k1 = base + tid;         // == base + m2 + 32*(tid>>5)
        const int k2b = k1 + 128;
        const float ang = -0.012271846303085130f * (float)k1;  // -pi/256 * k1
        const v2f cksk = { __cosf(ang), __sinf(ang) };
        v2f cs = { 1.f, 0.f };
        v2f Tx0 = {0,0}, Tx1 = {0,0}, Tx2 = {0,0}, Tx3 = {0,0};
        v2f Ty0 = {0,0}, Ty1 = {0,0}, Ty2 = {0,0}, Ty3 = {0,0};
        #pragma unroll
        for (int t0 = 0; t0 < 16; ++t0) {
            const v4f sv = sxy[t0 * 32 + m2];
            const v2f sx = sv.xy, sy = sv.zw;
            if ((t0 & 3) == 0)      { pk_fma_blo(Tx0, cs, sx); pk_fma_rot(Tx0, cs, sx);
                                      pk_fma_blo(Ty0, cs, sy); pk_fma_rot(Ty0, cs, sy); }
            else if ((t0 & 3) == 1) { pk_fma_blo(Tx1, cs, sx); pk_fma_rot(Tx1, cs, sx);
                                      pk_fma_blo(Ty1, cs, sy); pk_fma_rot(Ty1, cs, sy); }
            else if ((t0 & 3) == 2) { pk_fma_blo(Tx2, cs, sx); pk_fma_rot(Tx2, cs, sx);
                                      pk_fma_blo(Ty2, cs, sy); pk_fma_rot(Ty2, cs, sy); }
            else                    { pk_fma_blo(Tx3, cs, sx); pk_fma_rot(Tx3, cs, sx);
                                      pk_fma_blo(Ty3, cs, sy); pk_fma_rot(Ty3, cs, sy); }
            pk_rot(cs, cksk);
        }
        // combine: X1 = T0+T1+T2+T3 ; X2 = (T0-T2) - i (T1-T3)
        const v2f Ax = Tx0 + Tx2, Bx = Tx0 - Tx2, Cx = Tx1 + Tx3, Dx = Tx1 - Tx3;
        const v2f Ay = Ty0 + Ty2, By = Ty0 - Ty2, Cy = Ty1 + Ty3, Dy = Ty1 - Ty3;
        const v2f X1 = Ax + Cx;
        const v2f Y1 = Ay + Cy;
        const v2f X2 = { Bx.x + Dx.y, Bx.y - Dx.x };   // B - i*D
        const v2f Y2 = { By.x + Dy.y, By.y - Dy.x };
        if (k1 >= blo && k1 < bhi) {
            px[k1 - blo] = fmaf(X1.x, X1.x, X1.y * X1.y);
            py[k1 - blo] = fmaf(Y1.x, Y1.x, Y1.y * Y1.y);
        }
        if (k2b < bhi) {                    // k2b >= 128 > blo always
            px[k2b - blo] = fmaf(X2.x, X2.x, X2.y * X2.y);
            py[k2b - blo] = fmaf(Y2.x, Y2.x, Y2.y * Y2.y);
        }
    }
    __syncthreads();

    // Third-octave band sums: 4 threads per band, shuffle-reduce
    if (tid < 4 * NUMBAND) {
        const int band = tid >> 2, s = tid & 3;
        const int lo = band_lo[band], hi = band_hi[band];
        float ssum = 0.f;
        for (int k = lo + s; k < hi; k += 4) ssum += px[k - blo];
        ssum += __shfl_xor(ssum, 1, 64);
        ssum += __shfl_xor(ssum, 2, 64);
        if (s == 0) xtob[((size_t)b * NUMBAND + band) * NSTFT + j] = sqrtf(ssum + EPSF);
    } else if (tid >= 64 && tid < 64 + 4 * NUMBAND) {
        const int band = (tid - 64) >> 2, s = tid & 3;
        const int lo = band_lo[band], hi = band_hi[band];
        float ssum = 0.f;
        for (int k = lo + s; k < hi; k += 4) ssum += py[k - blo];
        ssum += __shfl_xor(ssum, 1, 64);
        ssum += __shfl_xor(ssum, 2, 64);
        if (s == 0) ytob[((size_t)b * NUMBAND + band) * NSTFT + j] = sqrtf(ssum + EPSF);
    }
}

__global__ __launch_bounds__(256)
void k3_corr(const float* __restrict__ xtob, const float* __restrict__ ytob,
             const int* __restrict__ counts, float* __restrict__ acc)
{
    const int bb = blockIdx.y;
    const int b = bb / NUMBAND;
    const int band = bb % NUMBAND;
    const int s_base = blockIdx.x * 256;
    const int tid = threadIdx.x;
    const int seg = s_base + tid;

    __shared__ float lx[256 + N_INTEL - 1], ly[256 + N_INTEL - 1];
    const float* xr = xtob + ((size_t)b * NUMBAND + band) * NSTFT;
    const float* yr = ytob + ((size_t)b * NUMBAND + band) * NSTFT;
    for (int i = tid; i < 256 + N_INTEL - 1; i += 256) {
        const int g = s_base + i;
        float vx = 0.f, vy = 0.f;
        if (g < NSTFT) { vx = xr[g]; vy = yr[g]; }
        lx[i] = vx; ly[i] = vy;
    }
    __syncthreads();

    int nvalid = counts[b] - N_INTEL;
    if (nvalid < 0) nvalid = 0;
    if (nvalid > NSEG) nvalid = NSEG;

    float d = 0.f;
    if (seg < nvalid) {
        float xv[N_INTEL], yv[N_INTEL];
        float sx2 = 0.f, sy2 = 0.f;
        #pragma unroll
        for (int i = 0; i < N_INTEL; ++i) {
            xv[i] = lx[tid + i]; yv[i] = ly[tid + i];
            sx2 = fmaf(xv[i], xv[i], sx2);
            sy2 = fmaf(yv[i], yv[i], sy2);
        }
        const float nc = sqrtf(sx2) / (sqrtf(sy2) + EPSF);
        float sy = 0.f, sx = 0.f;
        #pragma unroll
        for (int i = 0; i < N_INTEL; ++i) {
            const float yp = fminf(yv[i] * nc, xv[i] * (1.f + CLIP_VAL));
            yv[i] = yp;
            sy += yp; sx += xv[i];
        }
        const float my = sy * (1.f / N_INTEL);
        const float mxm = sx * (1.f / N_INTEL);
        float num = 0.f, dy = 0.f, dx2 = 0.f;
        #pragma unroll
        for (int i = 0; i < N_INTEL; ++i) {
            const float a = yv[i] - my;
            const float c = xv[i] - mxm;
            num = fmaf(a, c, num);
            dy  = fmaf(a, a, dy);
            dx2 = fmaf(c, c, dx2);
        }
        d = num / ((sqrtf(dy) + EPSF) * (sqrtf(dx2) + EPSF));
    }

    #pragma unroll
    for (int o = 32; o > 0; o >>= 1) d += __shfl_down(d, o, 64);
    __shared__ float wsum[4];
    const int lane = threadIdx.x & 63, wid = threadIdx.x >> 6;
    if (lane == 0) wsum[wid] = d;
    __syncthreads();
    if (threadIdx.x == 0) {
        atomicAdd(&acc[b], wsum[0] + wsum[1] + wsum[2] + wsum[3]);
    }
}

__global__ void k4_final(const float* __restrict__ acc, const int* __restrict__ counts,
                         float* __restrict__ out)
{
    const int b = threadIdx.x;
    if (b < NB) {
        int nvalid = counts[b] - N_INTEL;
        if (nvalid < 0) nvalid = 0;
        if (nvalid > NSEG) nvalid = NSEG;
        out[b] = -(acc[b] * (1.f / NUMBAND)) / ((float)nvalid + EPSF);
    }
}

extern "C" void kernel_launch(void* const* d_in, const int* in_sizes, int n_in,
                              void* d_out, int out_size, void* d_ws, size_t ws_size,
                              hipStream_t stream) {
    (void)in_sizes; (void)n_in; (void)out_size; (void)ws_size;
    const float* est = (const float*)d_in[0];
    const float* tgt = (const float*)d_in[1];
    const float* win = (const float*)d_in[2];
    const float* obm = (const float*)d_in[3];
    float* out = (float*)d_out;

    char* ws = (char*)d_ws;
    int*   counts  = (int*)(ws + WS_COUNTS);
    int*   band_lo = (int*)(ws + WS_BANDLO);
    int*   band_hi = (int*)(ws + WS_BANDHI);
    float* acc     = (float*)(ws + WS_ACC);
    int*   srcfrm  = (int*)(ws + WS_SRCFRM);
    float* xtob    = (float*)(ws + WS_XTOB);
    float* ytob    = (float*)(ws + WS_YTOB);
    float2* ab     = (float2*)xtob;  // scratch alias: consumed by k1b before k2 writes

    k1a_ab<<<dim3(NB, 10), dim3(256), 0, stream>>>(tgt, win, ab);
    k1b_scan<<<dim3(NB), dim3(256), 0, stream>>>(ab, obm, counts, srcfrm,
                                                 band_lo, band_hi, acc);
    k2_stft_tob<<<dim3(NSTFT, NB), dim3(128), 0, stream>>>(est, tgt, win, counts, srcfrm,
                                                           band_lo, band_hi, xtob, ytob);
    k3_corr<<<dim3((NSEG + 255) / 256, NB * NUMBAND), dim3(256), 0, stream>>>(xtob, ytob,
                                                                              counts, acc);
    k4_final<<<1, NB, 0, stream>>>(acc, counts, out);
}

// Round 7
// 193.735 us; speedup vs baseline: 4.7635x; 1.0228x over previous
//
#include <hip/hip_runtime.h>
#include <math.h>

#define EPSF 1e-8f
#define WIN_LEN 256
#define HOP 128
#define NBINS 257          // rfft bins of 512
#define NUMBAND 15
#define NFRAMES 2499       // (320000-256)/128+1
#define NSTFT 2498         // NFRAMES-1
#define N_INTEL 30
#define NSEG 2469          // NSTFT - N_INTEL + 1
#define NB 32              // batch
#define T_LEN 320000
#define CLIP_VAL 5.623413251903491f   // 10^(15/20)
#define NHALF 2500         // half-frames (T_LEN/HOP)
#define AB_STRIDE 2560

typedef float v2f __attribute__((ext_vector_type(2)));
typedef float v4f __attribute__((ext_vector_type(4)));

// ---- packed fp32 helpers (VOP3P) ----
// d += a * bcast(b.lo)
__device__ __forceinline__ void pk_fma_blo(v2f& d, v2f a, v2f b) {
    asm("v_pk_fma_f32 %0, %1, %2, %0 op_sel:[0,0,0] op_sel_hi:[1,0,1]"
        : "+v"(d) : "v"(a), "v"(b));
}
// d += a * bcast(b.hi)
__device__ __forceinline__ void pk_fma_bhi(v2f& d, v2f a, v2f b) {
    asm("v_pk_fma_f32 %0, %1, %2, %0 op_sel:[0,1,0] op_sel_hi:[1,1,1]"
        : "+v"(d) : "v"(a), "v"(b));
}
// d += (-a.hi*b.hi, a.lo*b.hi)
__device__ __forceinline__ void pk_fma_rot(v2f& d, v2f a, v2f b) {
    asm("v_pk_fma_f32 %0, %1, %2, %0 op_sel:[1,1,0] op_sel_hi:[0,1,1] neg_lo:[1,0,0]"
        : "+v"(d) : "v"(a), "v"(b));
}
// cs = cs * (ck + i sk)
__device__ __forceinline__ void pk_rot(v2f& cs, v2f cksk) {
    v2f t;
    asm("v_pk_mul_f32 %0, %1, %2 op_sel:[0,0] op_sel_hi:[1,0]"
        : "=v"(t) : "v"(cs), "v"(cksk));
    asm("v_pk_fma_f32 %0, %0, %1, %2 op_sel:[1,1,0] op_sel_hi:[0,1,1] neg_lo:[1,0,0]"
        : "+v"(cs) : "v"(cksk), "v"(t));
}
// return a (x) b  (complex multiply, packed (re,im))
__device__ __forceinline__ v2f pk_cmul(v2f a, v2f b) {
    v2f t;
    asm("v_pk_mul_f32 %0, %1, %2 op_sel:[0,0] op_sel_hi:[1,0]"
        : "=v"(t) : "v"(a), "v"(b));                       // (a.lo*b.lo, a.hi*b.lo)
    asm("v_pk_fma_f32 %0, %1, %2, %0 op_sel:[1,1,0] op_sel_hi:[0,1,1] neg_lo:[1,0,0]"
        : "+v"(t) : "v"(a), "v"(b));                       // += (-a.hi*b.hi, a.lo*b.hi)
    return t;
}

// ---- workspace layout (bytes) ----
#define WS_COUNTS   0
#define WS_BANDLO   512
#define WS_BANDHI   768
#define WS_ACC      1024
#define WS_SRCFRM   2048
#define WS_XTOB     324096     // ab scratch aliases this region (consumed before k2)
#define WS_YTOB     5120512

// Per-half-frame windowed energy partials: A[h] (low window), B[h] (high window).
// norm^2[f] = A[f] + B[f+1]. Each sample read exactly once.
__global__ __launch_bounds__(256)
void k1a_ab(const float* __restrict__ tgt, const float* __restrict__ win,
            float2* __restrict__ ab)
{
    const int b = blockIdx.x;
    const int h = blockIdx.y * 256 + threadIdx.x;
    if (h >= NHALF) return;
    const float* xp = tgt + (size_t)b * T_LEN + (size_t)h * HOP;
    float sa = 0.f, sb = 0.f;
    #pragma unroll 4
    for (int u = 0; u < HOP; u += 4) {
        const float4 xv = *(const float4*)(xp + u);
        const float4 wl = *(const float4*)(win + u);
        const float4 wh = *(const float4*)(win + HOP + u);
        float a;
        a = xv.x * wl.x; sa = fmaf(a, a, sa);
        a = xv.y * wl.y; sa = fmaf(a, a, sa);
        a = xv.z * wl.z; sa = fmaf(a, a, sa);
        a = xv.w * wl.w; sa = fmaf(a, a, sa);
        a = xv.x * wh.x; sb = fmaf(a, a, sb);
        a = xv.y * wh.y; sb = fmaf(a, a, sb);
        a = xv.z * wh.z; sb = fmaf(a, a, sb);
        a = xv.w * wh.w; sb = fmaf(a, a, sb);
    }
    ab[(size_t)b * AB_STRIDE + h] = make_float2(sa, sb);
}

__global__ __launch_bounds__(256)
void k1b_scan(const float2* __restrict__ ab, const float* __restrict__ obm,
              int* __restrict__ counts, int* __restrict__ srcfrm,
              int* __restrict__ band_lo, int* __restrict__ band_hi,
              float* __restrict__ acc)
{
    const int b = blockIdx.x;
    const int tid = threadIdx.x;
    __shared__ float nr[NFRAMES];
    __shared__ float red[256];
    __shared__ int   sc[256];

    const float2* abp = ab + (size_t)b * AB_STRIDE;
    for (int f = tid; f < NFRAMES; f += 256) {
        const float2 p0 = abp[f];
        const float2 p1 = abp[f + 1];
        nr[f] = sqrtf(p0.x + p1.y);
    }
    __syncthreads();

    float mx = 0.f;
    for (int f = tid; f < NFRAMES; f += 256) mx = fmaxf(mx, nr[f]);
    red[tid] = mx;
    __syncthreads();
    for (int s = 128; s > 0; s >>= 1) {
        if (tid < s) red[tid] = fmaxf(red[tid], red[tid + s]);
        __syncthreads();
    }
    const float thr = (red[0] + EPSF) * 0.01f;   // 10^(-40/20)

    const int c0 = tid * 10;
    const int c1 = (c0 + 10 < NFRAMES) ? c0 + 10 : NFRAMES;
    int lc = 0;
    for (int f = c0; f < c1; ++f) if (nr[f] + EPSF > thr) ++lc;
    sc[tid] = lc;
    __syncthreads();
    // Hillis-Steele inclusive scan over 256 partial counts
    #pragma unroll
    for (int off = 1; off < 256; off <<= 1) {
        int u = (tid >= off) ? sc[tid - off] : 0;
        __syncthreads();
        sc[tid] += u;
        __syncthreads();
    }
    if (tid == 0) {
        counts[b] = sc[255];
        acc[b] = 0.f;   // self-init accumulator every launch
    }
    int pos = sc[tid] - lc;   // exclusive prefix
    int* sf = srcfrm + b * NFRAMES;
    for (int f = c0; f < c1; ++f) if (nr[f] + EPSF > thr) sf[pos++] = f;

    if (b == 0 && tid < NUMBAND) {
        int lo = -1, hi = 0;
        for (int k = 0; k < NBINS; ++k) {
            if (obm[tid * NBINS + k] != 0.f) { if (lo < 0) lo = k; hi = k + 1; }
        }
        band_lo[tid] = (lo < 0) ? 0 : lo;
        band_hi[tid] = hi;
    }
    __syncthreads();
    if (b == 0 && tid == 0) {
        int lo = NBINS, hi = 0;
        for (int i = 0; i < NUMBAND; ++i) {
            if (band_lo[i] < lo) lo = band_lo[i];
            if (band_hi[i] > hi) hi = band_hi[i];
        }
        band_lo[NUMBAND] = lo;
        band_hi[NUMBAND] = hi;
    }
}

// Two-stage factorized DFT (512 = 32 x 16), 128 threads/block.
// Stage 1 (radix-4 m-split): thread (m<8, c<16) computes S[c][m+8j], j<4.
// Stage 2 (one wave, thread (m2<32, sig<2)): V[t0] = W512^{m2 t0} S[t0][m2]
//   (one twiddle chain), then X[m2+32p] = 16-pt DFT of V at freq p (radix-4,
//   hard-coded W16 twiddles) for p = 0..6 — covers all needed bins.
__global__ __launch_bounds__(128)
void k2_stft_tob(const float* __restrict__ est, const float* __restrict__ tgt,
                 const float* __restrict__ win,
                 const int* __restrict__ counts, const int* __restrict__ srcfrm,
                 const int* __restrict__ band_lo, const int* __restrict__ band_hi,
                 float* __restrict__ xtob, float* __restrict__ ytob)
{
    // bijective XCD-chunked remap (L2 locality for reads + tob writes)
    const int lin = blockIdx.x;
    const int xcd = lin & 7, cidx = lin >> 3;
    const int q = NSTFT >> 3, r = NSTFT & 7;
    const int j = (xcd < r ? xcd * (q + 1) : r * (q + 1) + (xcd - r) * q) + cidx;

    const int b = blockIdx.y;
    const int cntb = counts[b];
    if (j >= cntb - 1) return;    // masked frame; never consumed downstream

    const int tid = threadIdx.x;
    __shared__ v4f   sxy[512];    // stage-1 out {x.re,x.im,y.re,y.im}, idx t0*32+m
    __shared__ float frf[512];    // staging (x,y interleaved); aliased px/py later

    const int* sf = srcfrm + b * NFRAMES;
    const float* xg = tgt + (size_t)b * T_LEN;
    const float* yg = est + (size_t)b * T_LEN;

    // staging: thread tid builds samples (2 tid, 2 tid+1); wave-uniform branches
    {
        const int t2 = 2 * tid;
        const int k0 = sf[j];
        const v2f wa = *(const v2f*)&win[t2];
        v2f xv, yv;
        if (tid < 64) {                      // samples < HOP
            xv = *(const v2f*)&xg[k0 * HOP + t2] * wa;
            yv = *(const v2f*)&yg[k0 * HOP + t2] * wa;
            if (j >= 1) {
                const int km = sf[j - 1];
                const v2f wb = *(const v2f*)&win[HOP + t2];
                xv += *(const v2f*)&xg[km * HOP + HOP + t2] * wb;
                yv += *(const v2f*)&yg[km * HOP + HOP + t2] * wb;
            }
        } else {                             // samples >= HOP
            const int kp = sf[j + 1];
            const v2f wb = *(const v2f*)&win[t2 - HOP];
            xv = *(const v2f*)&xg[k0 * HOP + t2] * wa
               + *(const v2f*)&xg[kp * HOP + t2 - HOP] * wb;
            yv = *(const v2f*)&yg[k0 * HOP + t2] * wa
               + *(const v2f*)&yg[kp * HOP + t2 - HOP] * wb;
        }
        const v4f st = { xv.x * wa.x, yv.x * wa.x, xv.y * wa.y, yv.y * wa.y };
        *(v4f*)&frf[4 * tid] = st;
    }
    __syncthreads();

    // ---- Stage 1 (radix-4 m-split, one column per thread)
    {
        const int m = tid & 7;
        const int c = tid >> 3;            // column t0 = c, 0..15
        const float ang = -0.19634954084936207f * (float)m;  // -pi/16 * m
        const v2f cksk = { __cosf(ang), __sinf(ang) };
        v2f cs = { 1.f, 0.f };
        v2f Tx0 = {0,0}, Tx1 = {0,0}, Tx2 = {0,0}, Tx3 = {0,0};
        v2f Ty0 = {0,0}, Ty1 = {0,0}, Ty2 = {0,0}, Ty3 = {0,0};
        #pragma unroll
        for (int t1 = 0; t1 < 16; ++t1) {
            const v2f va = *(const v2f*)&frf[2 * (t1 * 16 + c)];
            if ((t1 & 3) == 0)      { pk_fma_blo(Tx0, cs, va); pk_fma_bhi(Ty0, cs, va); }
            else if ((t1 & 3) == 1) { pk_fma_blo(Tx1, cs, va); pk_fma_bhi(Ty1, cs, va); }
            else if ((t1 & 3) == 2) { pk_fma_blo(Tx2, cs, va); pk_fma_bhi(Ty2, cs, va); }
            else                    { pk_fma_blo(Tx3, cs, va); pk_fma_bhi(Ty3, cs, va); }
            pk_rot(cs, cksk);
        }
        const v2f Ax = Tx0 + Tx2, Bx = Tx0 - Tx2, Cx = Tx1 + Tx3, Dx = Tx1 - Tx3;
        const v2f Ay = Ty0 + Ty2, By = Ty0 - Ty2, Cy = Ty1 + Ty3, Dy = Ty1 - Ty3;
        const v2f S0x = Ax + Cx, S2x = Ax - Cx;
        const v2f S0y = Ay + Cy, S2y = Ay - Cy;
        const v2f S1x = { Bx.x + Dx.y, Bx.y - Dx.x };   // B - iD
        const v2f S1y = { By.x + Dy.y, By.y - Dy.x };
        const v2f S3x = { Bx.x - Dx.y, Bx.y + Dx.x };   // B + iD
        const v2f S3y = { By.x - Dy.y, By.y + Dy.x };
        sxy[c * 32 + m]      = (v4f){ S0x.x, S0x.y, S0y.x, S0y.y };
        sxy[c * 32 + m + 8]  = (v4f){ S1x.x, S1x.y, S1y.x, S1y.y };
        sxy[c * 32 + m + 16] = (v4f){ S2x.x, S2x.y, S2y.x, S2y.y };
        sxy[c * 32 + m + 24] = (v4f){ S3x.x, S3x.y, S3y.x, S3y.y };
    }
    __syncthreads();

    // ---- Stage 2: one wave; thread (m2, sig) -> 7 bins via 16-pt DFT
    const int blo = band_lo[NUMBAND];
    const int bhi = band_hi[NUMBAND];
    (void)bhi;
    const int base = blo & ~31;
    float* px = frf;            // alias: frf dead after stage 1; 224 slots
    float* py = frf + 224;
    if (tid < 64) {
        const int m2 = tid & 31;
        const int sig = tid >> 5;
        const int sbyte = m2 * 16 + sig * 8;
        const float ang = -0.012271846303085130f * (float)(base + m2);  // -pi/256*(base+m2)
        const v2f cksk = { __cosf(ang), __sinf(ang) };
        v2f cs = { 1.f, 0.f };
        v2f V[16];
        #pragma unroll
        for (int t0 = 0; t0 < 16; ++t0) {
            const v2f s = *(const v2f*)((const char*)sxy + (t0 * 512 + sbyte));
            V[t0] = (t0 == 0) ? s : pk_cmul(cs, s);
            pk_rot(cs, cksk);
        }
        // radix-4 over q (t0 = 4q + r): G[d][r] = sum_q W4^{dq} V[4q+r]
        v2f G[4][4];
        #pragma unroll
        for (int rr = 0; rr < 4; ++rr) {
            const v2f A = V[rr] + V[rr + 8];
            const v2f B = V[rr] - V[rr + 8];
            const v2f C = V[rr + 4] + V[rr + 12];
            const v2f D = V[rr + 4] - V[rr + 12];
            G[0][rr] = A + C;
            G[2][rr] = A - C;
            G[1][rr] = (v2f){ B.x + D.y, B.y - D.x };   // B - iD
            G[3][rr] = (v2f){ B.x - D.y, B.y + D.x };   // B + iD
        }
        float* pout = sig ? py : px;
        // X[p] = G[d][0] + W16^p G[d][1] + W16^{2p} G[d][2] + W16^{3p} G[d][3], d=p&3
        #define C1 0.92387953251f
        #define S1 0.38268343236f
        #define C2 0.70710678119f
        #define XOUT(P, D, W1R, W1I, W2R, W2I, W3R, W3I) { \
            float xr_ = G[D][0].x, xi_ = G[D][0].y; \
            xr_ += (W1R)*G[D][1].x - (W1I)*G[D][1].y; xi_ += (W1R)*G[D][1].y + (W1I)*G[D][1].x; \
            xr_ += (W2R)*G[D][2].x - (W2I)*G[D][2].y; xi_ += (W2R)*G[D][2].y + (W2I)*G[D][2].x; \
            xr_ += (W3R)*G[D][3].x - (W3I)*G[D][3].y; xi_ += (W3R)*G[D][3].y + (W3I)*G[D][3].x; \
            pout[(P) * 32 + m2] = fmaf(xr_, xr_, xi_ * xi_); }
        XOUT(0, 0,  1.f, 0.f,    1.f, 0.f,    1.f, 0.f)
        XOUT(1, 1,  C1, -S1,     C2, -C2,     S1, -C1)
        XOUT(2, 2,  C2, -C2,     0.f, -1.f,  -C2, -C2)
        XOUT(3, 3,  S1, -C1,    -C2, -C2,    -C1,  S1)
        XOUT(4, 0,  0.f, -1.f,  -1.f, 0.f,    0.f,  1.f)
        XOUT(5, 1, -S1, -C1,    -C2,  C2,     C1,  S1)
        XOUT(6, 2, -C2, -C2,     0.f,  1.f,   C2, -C2)
        #undef XOUT
    }
    __syncthreads();

    // Third-octave band sums: 4 threads per band, paired b64 reads, shuffle-reduce
    {
        const float* parr = (tid < 64) ? px : py;
        const int lt = (tid < 64) ? tid : tid - 64;
        if (lt < 4 * NUMBAND) {
            const int band = lt >> 2, s = lt & 3;
            const int lop = band_lo[band] - base, hip = band_hi[band] - base;
            const int u0 = lop >> 1, ul = (hip - 1) >> 1;
            float ssum = 0.f;
            for (int u = u0 + s; u <= ul; u += 4) {
                const v2f pv = *(const v2f*)&parr[2 * u];
                ssum += (2 * u >= lop ? pv.x : 0.f) + (2 * u + 1 < hip ? pv.y : 0.f);
            }
            ssum += __shfl_xor(ssum, 1, 64);
            ssum += __shfl_xor(ssum, 2, 64);
            if (s == 0) {
                float* tob = (tid < 64) ? xtob : ytob;
                tob[((size_t)b * NUMBAND + band) * NSTFT + j] = sqrtf(ssum + EPSF);
            }
        }
    }
}

__global__ __launch_bounds__(256)
void k3_corr(const float* __restrict__ xtob, const float* __restrict__ ytob,
             const int* __restrict__ counts, float* __restrict__ acc)
{
    const int bb = blockIdx.y;
    const int b = bb / NUMBAND;
    const int band = bb % NUMBAND;
    const int s_base = blockIdx.x * 256;
    const int tid = threadIdx.x;
    const int seg = s_base + tid;

    __shared__ v2f lxy[256 + N_INTEL - 1];
    const float* xr = xtob + ((size_t)b * NUMBAND + band) * NSTFT;
    const float* yr = ytob + ((size_t)b * NUMBAND + band) * NSTFT;
    for (int i = tid; i < 256 + N_INTEL - 1; i += 256) {
        const int g = s_base + i;
        v2f v = { 0.f, 0.f };
        if (g < NSTFT) v = (v2f){ xr[g], yr[g] };
        lxy[i] = v;
    }
    __syncthreads();

    int nvalid = counts[b] - N_INTEL;
    if (nvalid < 0) nvalid = 0;
    if (nvalid > NSEG) nvalid = NSEG;

    float d = 0.f;
    if (seg < nvalid) {
        float xv[N_INTEL], yv[N_INTEL];
        float sx2 = 0.f, sy2 = 0.f;
        #pragma unroll
        for (int i = 0; i < N_INTEL; ++i) {
            const v2f v = lxy[tid + i];
            xv[i] = v.x; yv[i] = v.y;
            sx2 = fmaf(xv[i], xv[i], sx2);
            sy2 = fmaf(yv[i], yv[i], sy2);
        }
        const float nc = sqrtf(sx2) / (sqrtf(sy2) + EPSF);
        float sy = 0.f, sx = 0.f;
        #pragma unroll
        for (int i = 0; i < N_INTEL; ++i) {
            const float yp = fminf(yv[i] * nc, xv[i] * (1.f + CLIP_VAL));
            yv[i] = yp;
            sy += yp; sx += xv[i];
        }
        const float my = sy * (1.f / N_INTEL);
        const float mxm = sx * (1.f / N_INTEL);
        float num = 0.f, dy = 0.f, dx2 = 0.f;
        #pragma unroll
        for (int i = 0; i < N_INTEL; ++i) {
            const float a = yv[i] - my;
            const float c = xv[i] - mxm;
            num = fmaf(a, c, num);
            dy  = fmaf(a, a, dy);
            dx2 = fmaf(c, c, dx2);
        }
        d = num / ((sqrtf(dy) + EPSF) * (sqrtf(dx2) + EPSF));
    }

    #pragma unroll
    for (int o = 32; o > 0; o >>= 1) d += __shfl_down(d, o, 64);
    __shared__ float wsum[4];
    const int lane = threadIdx.x & 63, wid = threadIdx.x >> 6;
    if (lane == 0) wsum[wid] = d;
    __syncthreads();
    if (threadIdx.x == 0) {
        atomicAdd(&acc[b], wsum[0] + wsum[1] + wsum[2] + wsum[3]);
    }
}

__global__ void k4_final(const float* __restrict__ acc, const int* __restrict__ counts,
                         float* __restrict__ out)
{
    const int b = threadIdx.x;
    if (b < NB) {
        int nvalid = counts[b] - N_INTEL;
        if (nvalid < 0) nvalid = 0;
        if (nvalid > NSEG) nvalid = NSEG;
        out[b] = -(acc[b] * (1.f / NUMBAND)) / ((float)nvalid + EPSF);
    }
}

extern "C" void kernel_launch(void* const* d_in, const int* in_sizes, int n_in,
                              void* d_out, int out_size, void* d_ws, size_t ws_size,
                              hipStream_t stream) {
    (void)in_sizes; (void)n_in; (void)out_size; (void)ws_size;
    const float* est = (const float*)d_in[0];
    const float* tgt = (const float*)d_in[1];
    const float* win = (const float*)d_in[2];
    const float* obm = (const float*)d_in[3];
    float* out = (float*)d_out;

    char* ws = (char*)d_ws;
    int*   counts  = (int*)(ws + WS_COUNTS);
    int*   band_lo = (int*)(ws + WS_BANDLO);
    int*   band_hi = (int*)(ws + WS_BANDHI);
    float* acc     = (float*)(ws + WS_ACC);
    int*   srcfrm  = (int*)(ws + WS_SRCFRM);
    float* xtob    = (float*)(ws + WS_XTOB);
    float* ytob    = (float*)(ws + WS_YTOB);
    float2* ab     = (float2*)xtob;  // scratch alias: consumed by k1b before k2 writes

    k1a_ab<<<dim3(NB, 10), dim3(256), 0, stream>>>(tgt, win, ab);
    k1b_scan<<<dim3(NB), dim3(256), 0, stream>>>(ab, obm, counts, srcfrm,
                                                 band_lo, band_hi, acc);
    k2_stft_tob<<<dim3(NSTFT, NB), dim3(128), 0, stream>>>(est, tgt, win, counts, srcfrm,
                                                           band_lo, band_hi, xtob, ytob);
    k3_corr<<<dim3((NSEG + 255) / 256, NB * NUMBAND), dim3(256), 0, stream>>>(xtob, ytob,
                                                                              counts, acc);
    k4_final<<<1, NB, 0, stream>>>(acc, counts, out);
}

// Round 8
// 191.047 us; speedup vs baseline: 4.8305x; 1.0141x over previous
//
#include <hip/hip_runtime.h>
#include <math.h>

#define EPSF 1e-8f
#define WIN_LEN 256
#define HOP 128
#define NBINS 257          // rfft bins of 512
#define NUMBAND 15
#define NFRAMES 2499       // (320000-256)/128+1
#define NSTFT 2498         // NFRAMES-1
#define N_INTEL 30
#define NSEG 2469          // NSTFT - N_INTEL + 1
#define NB 32              // batch
#define T_LEN 320000
#define CLIP_VAL 5.623413251903491f   // 10^(15/20)
#define NHALF 2500         // half-frames (T_LEN/HOP)
#define AB_STRIDE 2560

typedef float v2f __attribute__((ext_vector_type(2)));
typedef float v4f __attribute__((ext_vector_type(4)));

// ---- packed fp32 helpers (VOP3P) ----
// d += a * bcast(b.lo)
__device__ __forceinline__ void pk_fma_blo(v2f& d, v2f a, v2f b) {
    asm("v_pk_fma_f32 %0, %1, %2, %0 op_sel:[0,0,0] op_sel_hi:[1,0,1]"
        : "+v"(d) : "v"(a), "v"(b));
}
// d += (-a.hi*b.hi, a.lo*b.hi)
__device__ __forceinline__ void pk_fma_rot(v2f& d, v2f a, v2f b) {
    asm("v_pk_fma_f32 %0, %1, %2, %0 op_sel:[1,1,0] op_sel_hi:[0,1,1] neg_lo:[1,0,0]"
        : "+v"(d) : "v"(a), "v"(b));
}
// cs = cs * (ck + i sk)
__device__ __forceinline__ void pk_rot(v2f& cs, v2f cksk) {
    v2f t;
    asm("v_pk_mul_f32 %0, %1, %2 op_sel:[0,0] op_sel_hi:[1,0]"
        : "=v"(t) : "v"(cs), "v"(cksk));
    asm("v_pk_fma_f32 %0, %0, %1, %2 op_sel:[1,1,0] op_sel_hi:[0,1,1] neg_lo:[1,0,0]"
        : "+v"(cs) : "v"(cksk), "v"(t));
}
// return a (x) b  (complex multiply, packed (re,im))
__device__ __forceinline__ v2f pk_cmul(v2f a, v2f b) {
    v2f t;
    asm("v_pk_mul_f32 %0, %1, %2 op_sel:[0,0] op_sel_hi:[1,0]"
        : "=v"(t) : "v"(a), "v"(b));
    asm("v_pk_fma_f32 %0, %1, %2, %0 op_sel:[1,1,0] op_sel_hi:[0,1,1] neg_lo:[1,0,0]"
        : "+v"(t) : "v"(a), "v"(b));
    return t;
}

// ---- workspace layout (bytes) ----
#define WS_COUNTS   0
#define WS_BANDLO   512
#define WS_BANDHI   768
#define WS_ACC      1024
#define WS_SRCFRM   2048
#define WS_XTOB     324096     // ab scratch aliases this region (consumed before k2)
#define WS_YTOB     5120512

// Per-half-frame windowed energy partials: A[h] (low window), B[h] (high window).
__global__ __launch_bounds__(256)
void k1a_ab(const float* __restrict__ tgt, const float* __restrict__ win,
            float2* __restrict__ ab)
{
    const int b = blockIdx.x;
    const int h = blockIdx.y * 256 + threadIdx.x;
    if (h >= NHALF) return;
    const float* xp = tgt + (size_t)b * T_LEN + (size_t)h * HOP;
    float sa = 0.f, sb = 0.f;
    #pragma unroll 4
    for (int u = 0; u < HOP; u += 4) {
        const float4 xv = *(const float4*)(xp + u);
        const float4 wl = *(const float4*)(win + u);
        const float4 wh = *(const float4*)(win + HOP + u);
        float a;
        a = xv.x * wl.x; sa = fmaf(a, a, sa);
        a = xv.y * wl.y; sa = fmaf(a, a, sa);
        a = xv.z * wl.z; sa = fmaf(a, a, sa);
        a = xv.w * wl.w; sa = fmaf(a, a, sa);
        a = xv.x * wh.x; sb = fmaf(a, a, sb);
        a = xv.y * wh.y; sb = fmaf(a, a, sb);
        a = xv.z * wh.z; sb = fmaf(a, a, sb);
        a = xv.w * wh.w; sb = fmaf(a, a, sb);
    }
    ab[(size_t)b * AB_STRIDE + h] = make_float2(sa, sb);
}

__global__ __launch_bounds__(256)
void k1b_scan(const float2* __restrict__ ab, const float* __restrict__ obm,
              int* __restrict__ counts, int* __restrict__ srcfrm,
              int* __restrict__ band_lo, int* __restrict__ band_hi,
              float* __restrict__ acc)
{
    const int b = blockIdx.x;
    const int tid = threadIdx.x;
    __shared__ float nr[NFRAMES];
    __shared__ float red[256];
    __shared__ int   sc[256];

    const float2* abp = ab + (size_t)b * AB_STRIDE;
    for (int f = tid; f < NFRAMES; f += 256) {
        const float2 p0 = abp[f];
        const float2 p1 = abp[f + 1];
        nr[f] = sqrtf(p0.x + p1.y);
    }
    __syncthreads();

    float mx = 0.f;
    for (int f = tid; f < NFRAMES; f += 256) mx = fmaxf(mx, nr[f]);
    red[tid] = mx;
    __syncthreads();
    for (int s = 128; s > 0; s >>= 1) {
        if (tid < s) red[tid] = fmaxf(red[tid], red[tid + s]);
        __syncthreads();
    }
    const float thr = (red[0] + EPSF) * 0.01f;   // 10^(-40/20)

    const int c0 = tid * 10;
    const int c1 = (c0 + 10 < NFRAMES) ? c0 + 10 : NFRAMES;
    int lc = 0;
    for (int f = c0; f < c1; ++f) if (nr[f] + EPSF > thr) ++lc;
    sc[tid] = lc;
    __syncthreads();
    #pragma unroll
    for (int off = 1; off < 256; off <<= 1) {
        int u = (tid >= off) ? sc[tid - off] : 0;
        __syncthreads();
        sc[tid] += u;
        __syncthreads();
    }
    if (tid == 0) {
        counts[b] = sc[255];
        acc[b] = 0.f;   // self-init accumulator every launch
    }
    int pos = sc[tid] - lc;   // exclusive prefix
    int* sf = srcfrm + b * NFRAMES;
    for (int f = c0; f < c1; ++f) if (nr[f] + EPSF > thr) sf[pos++] = f;

    if (b == 0 && tid < NUMBAND) {
        int lo = -1, hi = 0;
        for (int k = 0; k < NBINS; ++k) {
            if (obm[tid * NBINS + k] != 0.f) { if (lo < 0) lo = k; hi = k + 1; }
        }
        band_lo[tid] = (lo < 0) ? 0 : lo;
        band_hi[tid] = hi;
    }
    __syncthreads();
    if (b == 0 && tid == 0) {
        int lo = NBINS, hi = 0;
        for (int i = 0; i < NUMBAND; ++i) {
            if (band_lo[i] < lo) lo = band_lo[i];
            if (band_hi[i] > hi) hi = band_hi[i];
        }
        band_lo[NUMBAND] = lo;
        band_hi[NUMBAND] = hi;
    }
}

// Single-wave (64-thread) two-stage DFT (512 = 32 x 16).
// Stage 1 (radix-8 m-split): thread (m<4, c<16) computes S[c][m+4j], j<8:
//   S[m+4j] = sum_{r<8} U_r W8^{jr},  U_r = W32^{mr} (z_r + (-i)^m z_{r+8}),
//   z_t1 = frame[16 t1 + c]  -> in-register 8-pt DIF FFT over r.
// Stage 2: thread (m2<32, sig<2): V[t0] = W512^{(base+m2) t0} S[t0][m2], then
//   16-pt radix-4 DFT of V at freqs p=0..6 -> bins base+m2+32p.
// S stored split SX/SY (float2), row stride 68 floats (272 B): all LDS
// accesses bank-audited to ideal depth.
__global__ __launch_bounds__(64)
void k2_stft_tob(const float* __restrict__ est, const float* __restrict__ tgt,
                 const float* __restrict__ win,
                 const int* __restrict__ counts, const int* __restrict__ srcfrm,
                 const int* __restrict__ band_lo, const int* __restrict__ band_hi,
                 float* __restrict__ xtob, float* __restrict__ ytob)
{
    // bijective XCD-chunked remap (L2 locality for reads + tob writes)
    const int lin = blockIdx.x;
    const int xcd = lin & 7, cidx = lin >> 3;
    const int q = NSTFT >> 3, r = NSTFT & 7;
    const int j = (xcd < r ? xcd * (q + 1) : r * (q + 1) + (xcd - r) * q) + cidx;

    const int b = blockIdx.y;
    const int cntb = counts[b];
    if (j >= cntb - 1) return;    // masked frame; never consumed downstream

    const int tid = threadIdx.x;  // 0..63
    __shared__ float frf[512];          // staging (x,y interleaved); px/py alias later
    __shared__ float sxr[2 * 16 * 68];  // SX rows [0,1088), SY rows [1088,2176)

    const int* sf = srcfrm + b * NFRAMES;
    const float* xg = tgt + (size_t)b * T_LEN;
    const float* yg = est + (size_t)b * T_LEN;

    // ---- staging: thread builds samples 4tid..4tid+3 (branch wave-uniform)
    {
        const int t4 = 4 * tid;
        const int k0 = sf[j];
        const v4f wa = *(const v4f*)&win[t4];
        v4f xv, yv;
        if (tid < 32) {                       // t < HOP
            xv = *(const v4f*)&xg[k0 * HOP + t4] * wa;
            yv = *(const v4f*)&yg[k0 * HOP + t4] * wa;
            if (j >= 1) {
                const int km = sf[j - 1];
                const v4f wb = *(const v4f*)&win[HOP + t4];
                xv += *(const v4f*)&xg[km * HOP + HOP + t4] * wb;
                yv += *(const v4f*)&yg[km * HOP + HOP + t4] * wb;
            }
        } else {                              // t >= HOP
            const int kp = sf[j + 1];
            const v4f wb = *(const v4f*)&win[t4 - HOP];
            xv = *(const v4f*)&xg[k0 * HOP + t4] * wa
               + *(const v4f*)&xg[kp * HOP + t4 - HOP] * wb;
            yv = *(const v4f*)&yg[k0 * HOP + t4] * wa
               + *(const v4f*)&yg[kp * HOP + t4 - HOP] * wb;
        }
        xv *= wa; yv *= wa;
        const v4f lo = { xv.x, yv.x, xv.y, yv.y };
        const v4f hi = { xv.z, yv.z, xv.w, yv.w };
        *(v4f*)&frf[2 * t4]     = lo;
        *(v4f*)&frf[2 * t4 + 4] = hi;
    }
    __syncthreads();

    // ---- Stage 1: radix-8 m-split, one column per thread
    {
        const int m = tid & 3;
        const int c = tid >> 2;            // 0..15
        // (-i)^m combine coefficients
        const float ke = (m == 0) ? 1.f : (m == 2) ? -1.f : 0.f;
        const float ki = (m == 1) ? -1.f : (m == 3) ? 1.f : 0.f;
        const float ang = -0.19634954084936207f * (float)m;  // -2pi m/32
        const float cm0 = __cosf(ang), sm0 = __sinf(ang);
        v2f URe[8], UIm[8];
        float cr = 1.f, sr = 0.f;
        #pragma unroll
        for (int rr = 0; rr < 8; ++rr) {
            const v2f za = *(const v2f*)&frf[2 * (16 * rr + c)];
            const v2f zb = *(const v2f*)&frf[2 * (16 * rr + 128 + c)];
            const v2f pre_re = za + ke * zb;   // packed (x,y) real parts
            const v2f pre_im = ki * zb;
            URe[rr] = cr * pre_re - sr * pre_im;
            UIm[rr] = sr * pre_re + cr * pre_im;
            const float crn = cr * cm0 - sr * sm0;
            sr = sr * cm0 + cr * sm0;
            cr = crn;
        }
        // 8-pt DIF FFT over r (complex, both signals packed per component)
        v2f ARe[8], AIm[8];
        {
            const float C2 = 0.70710678118654752f;
            #pragma unroll
            for (int rr = 0; rr < 4; ++rr) {
                ARe[rr] = URe[rr] + URe[rr + 4];
                AIm[rr] = UIm[rr] + UIm[rr + 4];
            }
            v2f dR, dI;
            ARe[4] = URe[0] - URe[4];           AIm[4] = UIm[0] - UIm[4];
            dR = URe[1] - URe[5]; dI = UIm[1] - UIm[5];
            ARe[5] = C2 * (dR + dI);            AIm[5] = C2 * (dI - dR);
            dR = URe[2] - URe[6]; dI = UIm[2] - UIm[6];
            ARe[6] = dI;                        AIm[6] = -dR;
            dR = URe[3] - URe[7]; dI = UIm[3] - UIm[7];
            ARe[7] = C2 * (dI - dR);            AIm[7] = -C2 * (dR + dI);
        }
        v2f BRe[8], BIm[8];
        #pragma unroll
        for (int g = 0; g < 8; g += 4) {
            BRe[g + 0] = ARe[g + 0] + ARe[g + 2];  BIm[g + 0] = AIm[g + 0] + AIm[g + 2];
            BRe[g + 1] = ARe[g + 1] + ARe[g + 3];  BIm[g + 1] = AIm[g + 1] + AIm[g + 3];
            BRe[g + 2] = ARe[g + 0] - ARe[g + 2];  BIm[g + 2] = AIm[g + 0] - AIm[g + 2];
            const v2f dR = ARe[g + 1] - ARe[g + 3], dI = AIm[g + 1] - AIm[g + 3];
            BRe[g + 3] = dI;  BIm[g + 3] = -dR;    // * (-i)
        }
        const int kmap[8] = { 0, 4, 2, 6, 1, 5, 3, 7 };   // DIF bitrev3
        #pragma unroll
        for (int p = 0; p < 8; ++p) {
            const int pb = p & ~1;
            const float sg = (p & 1) ? -1.f : 1.f;
            const v2f oR = BRe[pb] + sg * BRe[pb + 1];
            const v2f oI = BIm[pb] + sg * BIm[pb + 1];
            const int mj = m + 4 * kmap[p];
            *(v2f*)&sxr[c * 68 + mj * 2]        = (v2f){ oR.x, oI.x };
            *(v2f*)&sxr[1088 + c * 68 + mj * 2] = (v2f){ oR.y, oI.y };
        }
    }
    __syncthreads();

    // ---- Stage 2: thread (m2, sig) -> 7 bins via 16-pt radix-4 DFT
    const int blo = band_lo[NUMBAND];
    const int base = blo & ~31;
    float* px = frf;            // alias: frf dead after stage 1; 224 slots
    float* py = frf + 224;
    {
        const int m2 = tid & 31;
        const int sig = tid >> 5;
        const float* sbase = sxr + sig * 1088 + m2 * 2;
        const float ang = -0.012271846303085130f * (float)(base + m2);  // -pi/256*(base+m2)
        const v2f cksk = { __cosf(ang), __sinf(ang) };
        v2f cs = { 1.f, 0.f };
        v2f V[16];
        #pragma unroll
        for (int t0 = 0; t0 < 16; ++t0) {
            const v2f s = *(const v2f*)(sbase + t0 * 68);
            V[t0] = (t0 == 0) ? s : pk_cmul(cs, s);
            pk_rot(cs, cksk);
        }
        v2f G[4][4];
        #pragma unroll
        for (int rr = 0; rr < 4; ++rr) {
            const v2f A = V[rr] + V[rr + 8];
            const v2f B = V[rr] - V[rr + 8];
            const v2f C = V[rr + 4] + V[rr + 12];
            const v2f D = V[rr + 4] - V[rr + 12];
            G[0][rr] = A + C;
            G[2][rr] = A - C;
            G[1][rr] = (v2f){ B.x + D.y, B.y - D.x };   // B - iD
            G[3][rr] = (v2f){ B.x - D.y, B.y + D.x };   // B + iD
        }
        float* pout = sig ? py : px;
        #define C1 0.92387953251f
        #define S1 0.38268343236f
        #define C2c 0.70710678119f
        #define XOUT(P, D, W1R, W1I, W2R, W2I, W3R, W3I) { \
            float xr_ = G[D][0].x, xi_ = G[D][0].y; \
            xr_ += (W1R)*G[D][1].x - (W1I)*G[D][1].y; xi_ += (W1R)*G[D][1].y + (W1I)*G[D][1].x; \
            xr_ += (W2R)*G[D][2].x - (W2I)*G[D][2].y; xi_ += (W2R)*G[D][2].y + (W2I)*G[D][2].x; \
            xr_ += (W3R)*G[D][3].x - (W3I)*G[D][3].y; xi_ += (W3R)*G[D][3].y + (W3I)*G[D][3].x; \
            pout[(P) * 32 + m2] = fmaf(xr_, xr_, xi_ * xi_); }
        XOUT(0, 0,  1.f, 0.f,    1.f, 0.f,    1.f, 0.f)
        XOUT(1, 1,  C1, -S1,     C2c, -C2c,   S1, -C1)
        XOUT(2, 2,  C2c, -C2c,   0.f, -1.f,  -C2c, -C2c)
        XOUT(3, 3,  S1, -C1,    -C2c, -C2c,  -C1,  S1)
        XOUT(4, 0,  0.f, -1.f,  -1.f, 0.f,    0.f,  1.f)
        XOUT(5, 1, -S1, -C1,    -C2c,  C2c,   C1,  S1)
        XOUT(6, 2, -C2c, -C2c,   0.f,  1.f,   C2c, -C2c)
        #undef XOUT
    }
    __syncthreads();

    // ---- Third-octave band sums: 4 threads per band, both signals
    if (tid < 4 * NUMBAND) {
        const int band = tid >> 2, s = tid & 3;
        const int lop = band_lo[band] - base, hip = band_hi[band] - base;
        const int u0 = lop >> 1, ul = (hip - 1) >> 1;
        float sx = 0.f, sy = 0.f;
        for (int u = u0 + s; u <= ul; u += 4) {
            const v2f pvx = *(const v2f*)&px[2 * u];
            const v2f pvy = *(const v2f*)&py[2 * u];
            const float m0 = (2 * u >= lop) ? 1.f : 0.f;
            const float m1 = (2 * u + 1 < hip) ? 1.f : 0.f;
            sx = fmaf(m0, pvx.x, sx); sx = fmaf(m1, pvx.y, sx);
            sy = fmaf(m0, pvy.x, sy); sy = fmaf(m1, pvy.y, sy);
        }
        sx += __shfl_xor(sx, 1, 64);  sx += __shfl_xor(sx, 2, 64);
        sy += __shfl_xor(sy, 1, 64);  sy += __shfl_xor(sy, 2, 64);
        if (s == 0) {
            xtob[((size_t)b * NUMBAND + band) * NSTFT + j] = sqrtf(sx + EPSF);
            ytob[((size_t)b * NUMBAND + band) * NSTFT + j] = sqrtf(sy + EPSF);
        }
    }
}

__global__ __launch_bounds__(256)
void k3_corr(const float* __restrict__ xtob, const float* __restrict__ ytob,
             const int* __restrict__ counts, float* __restrict__ acc)
{
    const int bb = blockIdx.y;
    const int b = bb / NUMBAND;
    const int band = bb % NUMBAND;
    const int s_base = blockIdx.x * 256;
    const int tid = threadIdx.x;
    const int seg = s_base + tid;

    __shared__ v2f lxy[256 + N_INTEL - 1];
    const float* xr = xtob + ((size_t)b * NUMBAND + band) * NSTFT;
    const float* yr = ytob + ((size_t)b * NUMBAND + band) * NSTFT;
    for (int i = tid; i < 256 + N_INTEL - 1; i += 256) {
        const int g = s_base + i;
        v2f v = { 0.f, 0.f };
        if (g < NSTFT) v = (v2f){ xr[g], yr[g] };
        lxy[i] = v;
    }
    __syncthreads();

    int nvalid = counts[b] - N_INTEL;
    if (nvalid < 0) nvalid = 0;
    if (nvalid > NSEG) nvalid = NSEG;

    float d = 0.f;
    if (seg < nvalid) {
        float xv[N_INTEL], yv[N_INTEL];
        float sx2 = 0.f, sy2 = 0.f;
        #pragma unroll
        for (int i = 0; i < N_INTEL; ++i) {
            const v2f v = lxy[tid + i];
            xv[i] = v.x; yv[i] = v.y;
            sx2 = fmaf(xv[i], xv[i], sx2);
            sy2 = fmaf(yv[i], yv[i], sy2);
        }
        const float nc = sqrtf(sx2) / (sqrtf(sy2) + EPSF);
        float sy = 0.f, sx = 0.f;
        #pragma unroll
        for (int i = 0; i < N_INTEL; ++i) {
            const float yp = fminf(yv[i] * nc, xv[i] * (1.f + CLIP_VAL));
            yv[i] = yp;
            sy += yp; sx += xv[i];
        }
        const float my = sy * (1.f / N_INTEL);
        const float mxm = sx * (1.f / N_INTEL);
        float num = 0.f, dy = 0.f, dx2 = 0.f;
        #pragma unroll
        for (int i = 0; i < N_INTEL; ++i) {
            const float a = yv[i] - my;
            const float c = xv[i] - mxm;
            num = fmaf(a, c, num);
            dy  = fmaf(a, a, dy);
            dx2 = fmaf(c, c, dx2);
        }
        d = num / ((sqrtf(dy) + EPSF) * (sqrtf(dx2) + EPSF));
    }

    #pragma unroll
    for (int o = 32; o > 0; o >>= 1) d += __shfl_down(d, o, 64);
    __shared__ float wsum[4];
    const int lane = threadIdx.x & 63, wid = threadIdx.x >> 6;
    if (lane == 0) wsum[wid] = d;
    __syncthreads();
    if (threadIdx.x == 0) {
        atomicAdd(&acc[b], wsum[0] + wsum[1] + wsum[2] + wsum[3]);
    }
}

__global__ void k4_final(const float* __restrict__ acc, const int* __restrict__ counts,
                         float* __restrict__ out)
{
    const int b = threadIdx.x;
    if (b < NB) {
        int nvalid = counts[b] - N_INTEL;
        if (nvalid < 0) nvalid = 0;
        if (nvalid > NSEG) nvalid = NSEG;
        out[b] = -(acc[b] * (1.f / NUMBAND)) / ((float)nvalid + EPSF);
    }
}

extern "C" void kernel_launch(void* const* d_in, const int* in_sizes, int n_in,
                              void* d_out, int out_size, void* d_ws, size_t ws_size,
                              hipStream_t stream) {
    (void)in_sizes; (void)n_in; (void)out_size; (void)ws_size;
    const float* est = (const float*)d_in[0];
    const float* tgt = (const float*)d_in[1];
    const float* win = (const float*)d_in[2];
    const float* obm = (const float*)d_in[3];
    float* out = (float*)d_out;

    char* ws = (char*)d_ws;
    int*   counts  = (int*)(ws + WS_COUNTS);
    int*   band_lo = (int*)(ws + WS_BANDLO);
    int*   band_hi = (int*)(ws + WS_BANDHI);
    float* acc     = (float*)(ws + WS_ACC);
    int*   srcfrm  = (int*)(ws + WS_SRCFRM);
    float* xtob    = (float*)(ws + WS_XTOB);
    float* ytob    = (float*)(ws + WS_YTOB);
    float2* ab     = (float2*)xtob;  // scratch alias: consumed by k1b before k2 writes

    k1a_ab<<<dim3(NB, 10), dim3(256), 0, stream>>>(tgt, win, ab);
    k1b_scan<<<dim3(NB), dim3(256), 0, stream>>>(ab, obm, counts, srcfrm,
                                                 band_lo, band_hi, acc);
    k2_stft_tob<<<dim3(NSTFT, NB), dim3(64), 0, stream>>>(est, tgt, win, counts, srcfrm,
                                                          band_lo, band_hi, xtob, ytob);
    k3_corr<<<dim3((NSEG + 255) / 256, NB * NUMBAND), dim3(256), 0, stream>>>(xtob, ytob,
                                                                              counts, acc);
    k4_final<<<1, NB, 0, stream>>>(acc, counts, out);
}